// Round 18
// baseline (147.783 us; speedup 1.0000x reference)
//
#include <hip/hip_runtime.h>

typedef __attribute__((ext_vector_type(4)))  float f32x4;
typedef __attribute__((ext_vector_type(16))) float f32x16;
typedef __attribute__((ext_vector_type(8)))  short short8;
typedef __attribute__((ext_vector_type(4)))  unsigned short u16x4;
typedef __attribute__((ext_vector_type(4)))  unsigned int u32x4;
typedef __attribute__((ext_vector_type(2)))  unsigned int u32x2;

// float -> bf16, round-to-nearest-even
static __device__ __forceinline__ unsigned short f2bf(float f) {
    unsigned int u = __float_as_uint(f);
    unsigned int r = (u + 0x7FFFu + ((u >> 16) & 1u)) >> 16;
    return (unsigned short)r;
}

#if __has_builtin(__builtin_amdgcn_exp2f)
#define EXP2(x) __builtin_amdgcn_exp2f(x)
#else
#define EXP2(x) exp2f(x)
#endif

static __device__ __forceinline__ u32x2 swap32v(unsigned int a, unsigned int b) {
#if __has_builtin(__builtin_amdgcn_permlane32_swap)
    return __builtin_amdgcn_permlane32_swap(a, b, false, false);
#else
    asm("v_permlane32_swap_b32 %0, %1" : "+v"(a), "+v"(b));
    u32x2 r; r[0] = a; r[1] = b; return r;
#endif
}

// lgkm-drain + raw barrier (vmcnt NOT drained: K/V prefetches stay in flight)
static __device__ __forceinline__ void block_sync_lds() {
    asm volatile("s_waitcnt lgkmcnt(0)" ::: "memory");
    __builtin_amdgcn_s_barrier();
    asm volatile("" ::: "memory");
}

// 32^-0.5 * log2(e)
#define SCALE2Q 0.25503487756f

// ---------------------------------------------------------------------------
__global__ void prep_w_kernel(const float* __restrict__ wqk,
                              const float* __restrict__ wv,
                              unsigned short* __restrict__ W) {
    int idx = blockIdx.x * 256 + threadIdx.x;
    int o = idx >> 8, c = idx & 255;
    float v;
    if (o < 64) { v = wqk[o * 256 + c]; if (o < 32) v *= SCALE2Q; }
    else        { v = wv[(o - 64) * 256 + c]; }
    W[idx] = f2bf(v);
}

// ---------------------------------------------------------------------------
__global__ __launch_bounds__(256) void transpose_kernel(
        const float* __restrict__ x, unsigned short* __restrict__ xT) {
    __shared__ unsigned short tile[64][66];
    int b = blockIdx.x & 7;
    int rem = blockIdx.x >> 3;
    int ct = rem >> 6, st = rem & 63;
    int s0 = st * 64, c0 = ct * 64;
    int tid = threadIdx.x;
    int ss = tid & 63, cq = tid >> 6;
#pragma unroll
    for (int p = 0; p < 16; ++p) {
        int cc = p * 4 + cq;
        float v = x[(size_t)(b * 256 + c0 + cc) * 4096 + s0 + ss];
        tile[ss][cc] = f2bf(v);
    }
    __syncthreads();
#pragma unroll
    for (int p = 0; p < 8; ++p) {
        int idx = p * 256 + tid;
        int sr = idx >> 5, jj = idx & 31;
        unsigned int val = *(const unsigned int*)&tile[sr][jj * 2];
        *(unsigned int*)(xT + (size_t)(b * 4096 + s0 + sr) * 256 + c0 + jj * 2) = val;
    }
}

// ---------------------------------------------------------------------------
__global__ __launch_bounds__(256) void proj_kernel(
        const unsigned short* __restrict__ W,    // [320][256]
        const unsigned short* __restrict__ xT,   // [8][4096][256]
        unsigned short* __restrict__ qkT,        // [8][4096][64]
        unsigned short* __restrict__ vbuf) {     // [8][256][4096]
    const int b  = blockIdx.x & 7;
    const int sb = blockIdx.x >> 3;
    const int s0 = sb * 64;
    const int tid = threadIdx.x;
    const int w = tid >> 6, l = tid & 63;
    const int lg = l >> 4, ll = l & 15;
    const size_t xbase = (size_t)b * 4096 * 256;

    f32x4 acc[5][4];
#pragma unroll
    for (int ot = 0; ot < 5; ++ot)
#pragma unroll
        for (int st = 0; st < 4; ++st) acc[ot][st] = (f32x4)0.0f;

    for (int k0 = 0; k0 < 256; k0 += 32) {
        short8 bf[4], af[5];
#pragma unroll
        for (int st = 0; st < 4; ++st)
            bf[st] = *(const short8*)(xT + xbase + (size_t)(s0 + st * 16 + ll) * 256 + k0 + lg * 8);
#pragma unroll
        for (int ot = 0; ot < 5; ++ot)
            af[ot] = *(const short8*)(W + (size_t)(80 * w + ot * 16 + ll) * 256 + k0 + lg * 8);
#pragma unroll
        for (int ot = 0; ot < 5; ++ot)
#pragma unroll
            for (int st = 0; st < 4; ++st)
                acc[ot][st] = __builtin_amdgcn_mfma_f32_16x16x32_bf16(af[ot], bf[st], acc[ot][st], 0, 0, 0);
    }
#pragma unroll
    for (int ot = 0; ot < 5; ++ot) {
        int o0 = 80 * w + ot * 16 + lg * 4;
#pragma unroll
        for (int st = 0; st < 4; ++st) {
            int s = s0 + st * 16 + ll;
            if (o0 < 64) {
                u16x4 pk;
#pragma unroll
                for (int i = 0; i < 4; ++i) pk[i] = f2bf(acc[ot][st][i]);
                *(u16x4*)(qkT + (size_t)b * 4096 * 64 + (size_t)s * 64 + o0) = pk;
            } else {
#pragma unroll
                for (int i = 0; i < 4; ++i)
                    vbuf[(size_t)b * 256 * 4096 + (size_t)(o0 - 64 + i) * 4096 + s] = f2bf(acc[ot][st][i]);
            }
        }
    }
}

// ---------------------------------------------------------------------------
__global__ __launch_bounds__(256) void repack_v_kernel(
        const unsigned short* __restrict__ vbuf,   // [8][256][4096]
        unsigned short* __restrict__ vfrag) {      // [8][8][256][64][8]
    int idx = blockIdx.x * 256 + threadIdx.x;
    int l    = idx & 63;
    int kf16 = (idx >> 6) & 255;
    int ct4  = (idx >> 14) & 7;
    int b    = idx >> 17;
    int l31 = l & 31, l5 = l >> 5;
    short8 v = *(const short8*)(vbuf + (size_t)b * 256 * 4096
                                + (size_t)(32 * ct4 + l31) * 4096
                                + 16 * kf16 + 8 * l5);
    *(short8*)(vfrag + (size_t)idx * 8) = v;
}

// ---------------------------------------------------------------------------
__global__ __launch_bounds__(256) void repack_k_kernel(
        const unsigned short* __restrict__ qkT,    // [8][4096][64]
        unsigned short* __restrict__ kfrag) {      // [8][128][2][64][8]
    int idx = blockIdx.x * 256 + threadIdx.x;
    int l  = idx & 63;
    int h  = (idx >> 6) & 1;
    int t2 = (idx >> 7) & 127;
    int b  = idx >> 14;
    int l31 = l & 31, l5 = l >> 5;
    short8 v = *(const short8*)(qkT + (size_t)b * 4096 * 64
                                + (size_t)(32 * t2 + l31) * 64
                                + 32 + 16 * h + 8 * l5);
    *(short8*)(kfrag + (size_t)idx * 8) = v;
}

// ---------------------------------------------------------------------------
// Kernel 4: attention, P/C split, KVBLK=128 (32 phases). 768 thr = 12 waves,
// 1 block/CU. Producers (w0-3, 32 q each): per phase 8 QK MFMA (4 K-tiles,
// kfA/kfB rolling reg sets) + 4x EXPPACK + 8x ds_write_b128.
// Consumers (w4-11, 32 ch each): per phase 8 CKS = 32 ds_read_b128 +
// 32 PV MFMA + rolling vfrag loads. One lgkm-only barrier per 128 keys
// (half the barrier/phase-overhead count of the 64-key version).
// ---------------------------------------------------------------------------
__global__ __launch_bounds__(768, 3) void attn_kernel(
        const unsigned short* __restrict__ qkT,   // [8][4096][64] (q|k)
        const unsigned short* __restrict__ kfrag, // [8][128][2][64][8]
        const unsigned short* __restrict__ vfrag, // [8][8][256][64][8]
        const float* __restrict__ x,              // [8][256][4096]
        const float* __restrict__ gamma,
        float* __restrict__ out) {
    __shared__ unsigned short p_lds[2][4][8][64][8];  // 64 KiB [buf][qb][ks][lane][8]
    __shared__ float lsum_lds[128];

    const int b   = blockIdx.x & 7;          // batch == XCD (L2 pinning)
    const int sb  = blockIdx.x >> 3;         // 0..31
    const int s0  = sb * 128;
    const int w   = threadIdx.x >> 6;        // 0..11
    const int l   = threadIdx.x & 63;
    const int l5  = l >> 5, l31 = l & 31;

    const size_t qk_base = (size_t)b * 4096 * 64;
    const size_t bx_base = (size_t)b * 256 * 4096;

    if (w < 4) {
        // ================= PRODUCER: q-rows [s0+32w, +32) ===================
        const unsigned short* qrow = qkT + qk_base + (size_t)(s0 + 32 * w + l31) * 64;
        const short8 qf0 = *(const short8*)(qrow + 8 * l5);
        const short8 qf1 = *(const short8*)(qrow + 16 + 8 * l5);
        const unsigned short* kfp = kfrag + (size_t)b * 128 * 2 * 512 + 8 * l;
        const f32x16 z16 = (f32x16)0.0f;
        float psum = 0.f;

        // phase t covers key frags 8t..8t+7; kfA = 8t+0..3, kfB = 8t+4..7
        short8 kA0 = *(const short8*)(kfp + 0 * 512);
        short8 kA1 = *(const short8*)(kfp + 1 * 512);
        short8 kA2 = *(const short8*)(kfp + 2 * 512);
        short8 kA3 = *(const short8*)(kfp + 3 * 512);
        short8 kB0 = *(const short8*)(kfp + 4 * 512);
        short8 kB1 = *(const short8*)(kfp + 5 * 512);
        short8 kB2 = *(const short8*)(kfp + 6 * 512);
        short8 kB3 = *(const short8*)(kfp + 7 * 512);

#define EXPPACK(DD, PLO, PHI)                                                  \
    {                                                                          \
        float e0 = EXP2((DD)[0]),   e1 = EXP2((DD)[1]);                        \
        float e2 = EXP2((DD)[2]),   e3 = EXP2((DD)[3]);                        \
        float e4 = EXP2((DD)[4]),   e5 = EXP2((DD)[5]);                        \
        float e6 = EXP2((DD)[6]),   e7 = EXP2((DD)[7]);                        \
        float e8 = EXP2((DD)[8]),   e9 = EXP2((DD)[9]);                        \
        float e10 = EXP2((DD)[10]), e11 = EXP2((DD)[11]);                      \
        float e12 = EXP2((DD)[12]), e13 = EXP2((DD)[13]);                      \
        float e14 = EXP2((DD)[14]), e15 = EXP2((DD)[15]);                      \
        psum += (((e0 + e1) + (e2 + e3)) + ((e4 + e5) + (e6 + e7)))            \
              + (((e8 + e9) + (e10 + e11)) + ((e12 + e13) + (e14 + e15)));     \
        unsigned int c0, c1, c2, c3;                                           \
        asm("v_cvt_pk_bf16_f32 %0, %1, %2" : "=v"(c0) : "v"(e0), "v"(e1));     \
        asm("v_cvt_pk_bf16_f32 %0, %1, %2" : "=v"(c1) : "v"(e2), "v"(e3));     \
        asm("v_cvt_pk_bf16_f32 %0, %1, %2" : "=v"(c2) : "v"(e4), "v"(e5));     \
        asm("v_cvt_pk_bf16_f32 %0, %1, %2" : "=v"(c3) : "v"(e6), "v"(e7));     \
        u32x2 s0_ = swap32v(c0, c2);                                           \
        u32x2 s1_ = swap32v(c1, c3);                                           \
        u32x4 lo_; lo_[0] = s0_[0]; lo_[1] = s1_[0]; lo_[2] = s0_[1]; lo_[3] = s1_[1]; \
        PLO = __builtin_bit_cast(short8, lo_);                                 \
        unsigned int d0, d1, d2, d3;                                           \
        asm("v_cvt_pk_bf16_f32 %0, %1, %2" : "=v"(d0) : "v"(e8), "v"(e9));     \
        asm("v_cvt_pk_bf16_f32 %0, %1, %2" : "=v"(d1) : "v"(e10), "v"(e11));   \
        asm("v_cvt_pk_bf16_f32 %0, %1, %2" : "=v"(d2) : "v"(e12), "v"(e13));   \
        u32x2 s2_ = swap32v(d0, d2);                                           \
        asm("v_cvt_pk_bf16_f32 %0, %1, %2" : "=v"(d3) : "v"(e14), "v"(e15));   \
        u32x2 s3_ = swap32v(d1, d3);                                           \
        u32x4 hi_; hi_[0] = s2_[0]; hi_[1] = s3_[0]; hi_[2] = s2_[1]; hi_[3] = s3_[1]; \
        PHI = __builtin_bit_cast(short8, hi_);                                 \
    }

#define PRODUCE(T)                                                             \
    {                                                                          \
        const int tn_ = ((T) + 1) & 31;                                        \
        const int pb_ = (T) & 1;                                               \
        /* half A: keys 0..63 of phase */                                      \
        f32x16 dd0 = __builtin_amdgcn_mfma_f32_32x32x16_bf16(kA0, qf0, z16, 0, 0, 0); \
        dd0 = __builtin_amdgcn_mfma_f32_32x32x16_bf16(kA1, qf1, dd0, 0, 0, 0); \
        f32x16 dd1 = __builtin_amdgcn_mfma_f32_32x32x16_bf16(kA2, qf0, z16, 0, 0, 0); \
        dd1 = __builtin_amdgcn_mfma_f32_32x32x16_bf16(kA3, qf1, dd1, 0, 0, 0); \
        kA0 = *(const short8*)(kfp + (size_t)(8 * tn_ + 0) * 512);             \
        kA1 = *(const short8*)(kfp + (size_t)(8 * tn_ + 1) * 512);             \
        kA2 = *(const short8*)(kfp + (size_t)(8 * tn_ + 2) * 512);             \
        kA3 = *(const short8*)(kfp + (size_t)(8 * tn_ + 3) * 512);             \
        short8 pa0, pa1, pa2, pa3;                                             \
        EXPPACK(dd0, pa0, pa1)                                                 \
        EXPPACK(dd1, pa2, pa3)                                                 \
        *(short8*)&p_lds[pb_][w][0][l][0] = pa0;                               \
        *(short8*)&p_lds[pb_][w][1][l][0] = pa1;                               \
        *(short8*)&p_lds[pb_][w][2][l][0] = pa2;                               \
        *(short8*)&p_lds[pb_][w][3][l][0] = pa3;                               \
        /* half B: keys 64..127 of phase */                                    \
        f32x16 dd2 = __builtin_amdgcn_mfma_f32_32x32x16_bf16(kB0, qf0, z16, 0, 0, 0); \
        dd2 = __builtin_amdgcn_mfma_f32_32x32x16_bf16(kB1, qf1, dd2, 0, 0, 0); \
        f32x16 dd3 = __builtin_amdgcn_mfma_f32_32x32x16_bf16(kB2, qf0, z16, 0, 0, 0); \
        dd3 = __builtin_amdgcn_mfma_f32_32x32x16_bf16(kB3, qf1, dd3, 0, 0, 0); \
        kB0 = *(const short8*)(kfp + (size_t)(8 * tn_ + 4) * 512);             \
        kB1 = *(const short8*)(kfp + (size_t)(8 * tn_ + 5) * 512);             \
        kB2 = *(const short8*)(kfp + (size_t)(8 * tn_ + 6) * 512);             \
        kB3 = *(const short8*)(kfp + (size_t)(8 * tn_ + 7) * 512);             \
        short8 pb0, pb1, pb2, pb3;                                             \
        EXPPACK(dd2, pb0, pb1)                                                 \
        EXPPACK(dd3, pb2, pb3)                                                 \
        *(short8*)&p_lds[pb_][w][4][l][0] = pb0;                               \
        *(short8*)&p_lds[pb_][w][5][l][0] = pb1;                               \
        *(short8*)&p_lds[pb_][w][6][l][0] = pb2;                               \
        *(short8*)&p_lds[pb_][w][7][l][0] = pb3;                               \
    }

        PRODUCE(0)
        for (int t = 1; t < 32; ++t) {
            block_sync_lds();
            PRODUCE(t)
        }
        block_sync_lds();
#undef PRODUCE
#undef EXPPACK

        psum += __shfl_xor(psum, 32);
        if (l5 == 0) lsum_lds[32 * w + l31] = psum;
        __syncthreads();
    } else {
        // ================= CONSUMER: channels [32(w-4), +32) ================
        const int cw = w - 4;                 // 0..7
        const int ch = 32 * cw + l31;
        const unsigned short* vfp = vfrag + ((size_t)(b * 8 + cw) * 256) * 512 + 8 * l;

        f32x16 acc0 = (f32x16)0.0f, acc1 = (f32x16)0.0f;
        f32x16 acc2 = (f32x16)0.0f, acc3 = (f32x16)0.0f;
        short8 vf0 = *(const short8*)(vfp + 0 * 512);   // slot A (even ks)
        short8 vf1 = *(const short8*)(vfp + 1 * 512);   // slot B (odd ks)

#define CKS(KS, VF)                                                            \
        {                                                                      \
            short8 p0 = *(const short8*)&p_lds[pb][0][KS][l][0];               \
            short8 p1 = *(const short8*)&p_lds[pb][1][KS][l][0];               \
            short8 p2 = *(const short8*)&p_lds[pb][2][KS][l][0];               \
            short8 p3 = *(const short8*)&p_lds[pb][3][KS][l][0];               \
            acc0 = __builtin_amdgcn_mfma_f32_32x32x16_bf16(p0, VF, acc0, 0, 0, 0); \
            acc1 = __builtin_amdgcn_mfma_f32_32x32x16_bf16(p1, VF, acc1, 0, 0, 0); \
            acc2 = __builtin_amdgcn_mfma_f32_32x32x16_bf16(p2, VF, acc2, 0, 0, 0); \
            acc3 = __builtin_amdgcn_mfma_f32_32x32x16_bf16(p3, VF, acc3, 0, 0, 0); \
        }

        for (int t = 0; t < 32; ++t) {
            block_sync_lds();
            const int pb = t & 1;
            const int f0 = 8 * t;
            const int fn = 8 * ((t + 1) & 31);
            CKS(0, vf0)
            vf0 = *(const short8*)(vfp + (size_t)(f0 + 2) * 512);
            CKS(1, vf1)
            vf1 = *(const short8*)(vfp + (size_t)(f0 + 3) * 512);
            CKS(2, vf0)
            vf0 = *(const short8*)(vfp + (size_t)(f0 + 4) * 512);
            CKS(3, vf1)
            vf1 = *(const short8*)(vfp + (size_t)(f0 + 5) * 512);
            CKS(4, vf0)
            vf0 = *(const short8*)(vfp + (size_t)(f0 + 6) * 512);
            CKS(5, vf1)
            vf1 = *(const short8*)(vfp + (size_t)(f0 + 7) * 512);
            CKS(6, vf0)
            vf0 = *(const short8*)(vfp + (size_t)(fn + 0) * 512);
            CKS(7, vf1)
            vf1 = *(const short8*)(vfp + (size_t)(fn + 1) * 512);
        }
#undef CKS
        __syncthreads();     // producers' lsum_lds writes now visible

        // ---- epilogue: out = gamma*acc/lsum + x ----
        const float g = gamma[0];
#pragma unroll
        for (int rq = 0; rq < 4; ++rq) {
            const int rbase = 8 * rq + 4 * l5;
#define STORE_QB(ACC, QB)                                                      \
            {                                                                  \
                f32x4 ls = *(const f32x4*)&lsum_lds[32 * (QB) + rbase];        \
                f32x4 gi;                                                      \
                gi[0] = g / ls[0]; gi[1] = g / ls[1];                          \
                gi[2] = g / ls[2]; gi[3] = g / ls[3];                          \
                size_t off = bx_base + (size_t)ch * 4096 + s0 + 32 * (QB) + rbase; \
                f32x4 xv = *(const f32x4*)(x + off);                           \
                f32x4 o;                                                       \
                o[0] = gi[0] * (ACC)[4 * rq + 0] + xv[0];                      \
                o[1] = gi[1] * (ACC)[4 * rq + 1] + xv[1];                      \
                o[2] = gi[2] * (ACC)[4 * rq + 2] + xv[2];                      \
                o[3] = gi[3] * (ACC)[4 * rq + 3] + xv[3];                      \
                *(f32x4*)(out + off) = o;                                      \
            }
            STORE_QB(acc0, 0)
            STORE_QB(acc1, 1)
            STORE_QB(acc2, 2)
            STORE_QB(acc3, 3)
#undef STORE_QB
        }
    }
}

// ---------------------------------------------------------------------------
extern "C" void kernel_launch(void* const* d_in, const int* in_sizes, int n_in,
                              void* d_out, int out_size, void* d_ws, size_t ws_size,
                              hipStream_t stream) {
    const float* x     = (const float*)d_in[0];
    const float* wqk   = (const float*)d_in[1];
    const float* wv    = (const float*)d_in[2];
    const float* gamma = (const float*)d_in[3];
    float* out = (float*)d_out;

    char* ws = (char*)d_ws;
    unsigned short* W     = (unsigned short*)(ws);                      // 160 KiB
    unsigned short* qkT   = (unsigned short*)(ws + 163840);             // 4 MiB
    unsigned short* xT    = (unsigned short*)(ws + 4358144);            // 16 MiB (-> vfrag)
    unsigned short* vbuf  = (unsigned short*)(ws + 21135360);           // 16 MiB
    unsigned short* kfrag = (unsigned short*)(ws + 37912576);           // 2 MiB
    unsigned short* vfrag = xT;   // reuse xT region (dead after proj)

    hipLaunchKernelGGL(prep_w_kernel,    dim3(320),  dim3(256), 0, stream, wqk, wv, W);
    hipLaunchKernelGGL(transpose_kernel, dim3(2048), dim3(256), 0, stream, x, xT);
    hipLaunchKernelGGL(proj_kernel,      dim3(512),  dim3(256), 0, stream, W, xT, qkT, vbuf);
    hipLaunchKernelGGL(repack_v_kernel,  dim3(4096), dim3(256), 0, stream, vbuf, vfrag);
    hipLaunchKernelGGL(repack_k_kernel,  dim3(512),  dim3(256), 0, stream, qkT, kfrag);
    hipLaunchKernelGGL(attn_kernel,      dim3(256),  dim3(768), 0, stream, qkT, kfrag, vfrag, x, gamma, out);
}

// Round 19
// 143.257 us; speedup vs baseline: 1.0316x; 1.0316x over previous
//
#include <hip/hip_runtime.h>

typedef __attribute__((ext_vector_type(4)))  float f32x4;
typedef __attribute__((ext_vector_type(16))) float f32x16;
typedef __attribute__((ext_vector_type(8)))  short short8;
typedef __attribute__((ext_vector_type(4)))  unsigned short u16x4;
typedef __attribute__((ext_vector_type(4)))  unsigned int u32x4;
typedef __attribute__((ext_vector_type(2)))  unsigned int u32x2;

// float -> bf16, round-to-nearest-even
static __device__ __forceinline__ unsigned short f2bf(float f) {
    unsigned int u = __float_as_uint(f);
    unsigned int r = (u + 0x7FFFu + ((u >> 16) & 1u)) >> 16;
    return (unsigned short)r;
}

#if __has_builtin(__builtin_amdgcn_exp2f)
#define EXP2(x) __builtin_amdgcn_exp2f(x)
#else
#define EXP2(x) exp2f(x)
#endif

static __device__ __forceinline__ u32x2 swap32v(unsigned int a, unsigned int b) {
#if __has_builtin(__builtin_amdgcn_permlane32_swap)
    return __builtin_amdgcn_permlane32_swap(a, b, false, false);
#else
    asm("v_permlane32_swap_b32 %0, %1" : "+v"(a), "+v"(b));
    u32x2 r; r[0] = a; r[1] = b; return r;
#endif
}

// lgkm-drain + raw barrier (vmcnt NOT drained: K/V prefetches stay in flight)
static __device__ __forceinline__ void block_sync_lds() {
    asm volatile("s_waitcnt lgkmcnt(0)" ::: "memory");
    __builtin_amdgcn_s_barrier();
    asm volatile("" ::: "memory");
}

// 32^-0.5 * log2(e)
#define SCALE2Q 0.25503487756f

// ---------------------------------------------------------------------------
__global__ void prep_w_kernel(const float* __restrict__ wqk,
                              const float* __restrict__ wv,
                              unsigned short* __restrict__ W) {
    int idx = blockIdx.x * 256 + threadIdx.x;
    int o = idx >> 8, c = idx & 255;
    float v;
    if (o < 64) { v = wqk[o * 256 + c]; if (o < 32) v *= SCALE2Q; }
    else        { v = wv[(o - 64) * 256 + c]; }
    W[idx] = f2bf(v);
}

// ---------------------------------------------------------------------------
__global__ __launch_bounds__(256) void transpose_kernel(
        const float* __restrict__ x, unsigned short* __restrict__ xT) {
    __shared__ unsigned short tile[64][66];
    int b = blockIdx.x & 7;
    int rem = blockIdx.x >> 3;
    int ct = rem >> 6, st = rem & 63;
    int s0 = st * 64, c0 = ct * 64;
    int tid = threadIdx.x;
    int ss = tid & 63, cq = tid >> 6;
#pragma unroll
    for (int p = 0; p < 16; ++p) {
        int cc = p * 4 + cq;
        float v = x[(size_t)(b * 256 + c0 + cc) * 4096 + s0 + ss];
        tile[ss][cc] = f2bf(v);
    }
    __syncthreads();
#pragma unroll
    for (int p = 0; p < 8; ++p) {
        int idx = p * 256 + tid;
        int sr = idx >> 5, jj = idx & 31;
        unsigned int val = *(const unsigned int*)&tile[sr][jj * 2];
        *(unsigned int*)(xT + (size_t)(b * 4096 + s0 + sr) * 256 + c0 + jj * 2) = val;
    }
}

// ---------------------------------------------------------------------------
__global__ __launch_bounds__(256) void proj_kernel(
        const unsigned short* __restrict__ W,    // [320][256]
        const unsigned short* __restrict__ xT,   // [8][4096][256]
        unsigned short* __restrict__ qkT,        // [8][4096][64]
        unsigned short* __restrict__ vbuf) {     // [8][256][4096]
    const int b  = blockIdx.x & 7;
    const int sb = blockIdx.x >> 3;
    const int s0 = sb * 64;
    const int tid = threadIdx.x;
    const int w = tid >> 6, l = tid & 63;
    const int lg = l >> 4, ll = l & 15;
    const size_t xbase = (size_t)b * 4096 * 256;

    f32x4 acc[5][4];
#pragma unroll
    for (int ot = 0; ot < 5; ++ot)
#pragma unroll
        for (int st = 0; st < 4; ++st) acc[ot][st] = (f32x4)0.0f;

    for (int k0 = 0; k0 < 256; k0 += 32) {
        short8 bf[4], af[5];
#pragma unroll
        for (int st = 0; st < 4; ++st)
            bf[st] = *(const short8*)(xT + xbase + (size_t)(s0 + st * 16 + ll) * 256 + k0 + lg * 8);
#pragma unroll
        for (int ot = 0; ot < 5; ++ot)
            af[ot] = *(const short8*)(W + (size_t)(80 * w + ot * 16 + ll) * 256 + k0 + lg * 8);
#pragma unroll
        for (int ot = 0; ot < 5; ++ot)
#pragma unroll
            for (int st = 0; st < 4; ++st)
                acc[ot][st] = __builtin_amdgcn_mfma_f32_16x16x32_bf16(af[ot], bf[st], acc[ot][st], 0, 0, 0);
    }
#pragma unroll
    for (int ot = 0; ot < 5; ++ot) {
        int o0 = 80 * w + ot * 16 + lg * 4;
#pragma unroll
        for (int st = 0; st < 4; ++st) {
            int s = s0 + st * 16 + ll;
            if (o0 < 64) {
                u16x4 pk;
#pragma unroll
                for (int i = 0; i < 4; ++i) pk[i] = f2bf(acc[ot][st][i]);
                *(u16x4*)(qkT + (size_t)b * 4096 * 64 + (size_t)s * 64 + o0) = pk;
            } else {
#pragma unroll
                for (int i = 0; i < 4; ++i)
                    vbuf[(size_t)b * 256 * 4096 + (size_t)(o0 - 64 + i) * 4096 + s] = f2bf(acc[ot][st][i]);
            }
        }
    }
}

// ---------------------------------------------------------------------------
__global__ __launch_bounds__(256) void repack_v_kernel(
        const unsigned short* __restrict__ vbuf,   // [8][256][4096]
        unsigned short* __restrict__ vfrag) {      // [8][8][256][64][8]
    int idx = blockIdx.x * 256 + threadIdx.x;
    int l    = idx & 63;
    int kf16 = (idx >> 6) & 255;
    int ct4  = (idx >> 14) & 7;
    int b    = idx >> 17;
    int l31 = l & 31, l5 = l >> 5;
    short8 v = *(const short8*)(vbuf + (size_t)b * 256 * 4096
                                + (size_t)(32 * ct4 + l31) * 4096
                                + 16 * kf16 + 8 * l5);
    *(short8*)(vfrag + (size_t)idx * 8) = v;
}

// ---------------------------------------------------------------------------
__global__ __launch_bounds__(256) void repack_k_kernel(
        const unsigned short* __restrict__ qkT,    // [8][4096][64]
        unsigned short* __restrict__ kfrag) {      // [8][128][2][64][8]
    int idx = blockIdx.x * 256 + threadIdx.x;
    int l  = idx & 63;
    int h  = (idx >> 6) & 1;
    int t2 = (idx >> 7) & 127;
    int b  = idx >> 14;
    int l31 = l & 31, l5 = l >> 5;
    short8 v = *(const short8*)(qkT + (size_t)b * 4096 * 64
                                + (size_t)(32 * t2 + l31) * 64
                                + 32 + 16 * h + 8 * l5);
    *(short8*)(kfrag + (size_t)idx * 8) = v;
}

// ---------------------------------------------------------------------------
// Kernel 4: attention, P/C split, KVBLK=64, full-phase V prefetch + setprio.
// 768 thr = 12 waves, 1 block/CU. Producers (w0-3, 32 q): setprio'd QK
// cluster -> exp2 -> cvt_pk+permlane -> 4x ds_write_b128. Consumers
// (w4-11, 32 ch): at phase start issue ALL 4 next-tile V loads (full-phase
// latency slack, ~3700cy >> L2 latency), then setprio'd 16-MFMA CKS
// cluster using the V set loaded LAST phase (named vC/vN, 2-step unroll).
// ---------------------------------------------------------------------------
__global__ __launch_bounds__(768, 3) void attn_kernel(
        const unsigned short* __restrict__ qkT,   // [8][4096][64] (q|k)
        const unsigned short* __restrict__ kfrag, // [8][128][2][64][8]
        const unsigned short* __restrict__ vfrag, // [8][8][256][64][8]
        const float* __restrict__ x,              // [8][256][4096]
        const float* __restrict__ gamma,
        float* __restrict__ out) {
    __shared__ unsigned short p_lds[2][4][4][64][8];  // 32 KiB [buf][qb][ks][lane][8]
    __shared__ float lsum_lds[128];

    const int b   = blockIdx.x & 7;          // batch == XCD (L2 pinning)
    const int sb  = blockIdx.x >> 3;         // 0..31
    const int s0  = sb * 128;
    const int w   = threadIdx.x >> 6;        // 0..11
    const int l   = threadIdx.x & 63;
    const int l5  = l >> 5, l31 = l & 31;

    const size_t qk_base = (size_t)b * 4096 * 64;
    const size_t bx_base = (size_t)b * 256 * 4096;

    if (w < 4) {
        // ================= PRODUCER: q-rows [s0+32w, +32) ===================
        const unsigned short* qrow = qkT + qk_base + (size_t)(s0 + 32 * w + l31) * 64;
        const short8 qf0 = *(const short8*)(qrow + 8 * l5);
        const short8 qf1 = *(const short8*)(qrow + 16 + 8 * l5);
        const unsigned short* kfp = kfrag + (size_t)b * 128 * 2 * 512 + 8 * l;
        const f32x16 z16 = (f32x16)0.0f;
        float psum = 0.f;

        short8 kf00 = *(const short8*)(kfp + 0 * 512);
        short8 kf01 = *(const short8*)(kfp + 1 * 512);
        short8 kf10 = *(const short8*)(kfp + 2 * 512);
        short8 kf11 = *(const short8*)(kfp + 3 * 512);

#define EXPPACK(DD, PLO, PHI)                                                  \
    {                                                                          \
        float e0 = EXP2((DD)[0]),   e1 = EXP2((DD)[1]);                        \
        float e2 = EXP2((DD)[2]),   e3 = EXP2((DD)[3]);                        \
        float e4 = EXP2((DD)[4]),   e5 = EXP2((DD)[5]);                        \
        float e6 = EXP2((DD)[6]),   e7 = EXP2((DD)[7]);                        \
        float e8 = EXP2((DD)[8]),   e9 = EXP2((DD)[9]);                        \
        float e10 = EXP2((DD)[10]), e11 = EXP2((DD)[11]);                      \
        float e12 = EXP2((DD)[12]), e13 = EXP2((DD)[13]);                      \
        float e14 = EXP2((DD)[14]), e15 = EXP2((DD)[15]);                      \
        psum += (((e0 + e1) + (e2 + e3)) + ((e4 + e5) + (e6 + e7)))            \
              + (((e8 + e9) + (e10 + e11)) + ((e12 + e13) + (e14 + e15)));     \
        unsigned int c0, c1, c2, c3;                                           \
        asm("v_cvt_pk_bf16_f32 %0, %1, %2" : "=v"(c0) : "v"(e0), "v"(e1));     \
        asm("v_cvt_pk_bf16_f32 %0, %1, %2" : "=v"(c1) : "v"(e2), "v"(e3));     \
        asm("v_cvt_pk_bf16_f32 %0, %1, %2" : "=v"(c2) : "v"(e4), "v"(e5));     \
        asm("v_cvt_pk_bf16_f32 %0, %1, %2" : "=v"(c3) : "v"(e6), "v"(e7));     \
        u32x2 s0_ = swap32v(c0, c2);                                           \
        u32x2 s1_ = swap32v(c1, c3);                                           \
        u32x4 lo_; lo_[0] = s0_[0]; lo_[1] = s1_[0]; lo_[2] = s0_[1]; lo_[3] = s1_[1]; \
        PLO = __builtin_bit_cast(short8, lo_);                                 \
        unsigned int d0, d1, d2, d3;                                           \
        asm("v_cvt_pk_bf16_f32 %0, %1, %2" : "=v"(d0) : "v"(e8), "v"(e9));     \
        asm("v_cvt_pk_bf16_f32 %0, %1, %2" : "=v"(d1) : "v"(e10), "v"(e11));   \
        asm("v_cvt_pk_bf16_f32 %0, %1, %2" : "=v"(d2) : "v"(e12), "v"(e13));   \
        u32x2 s2_ = swap32v(d0, d2);                                           \
        asm("v_cvt_pk_bf16_f32 %0, %1, %2" : "=v"(d3) : "v"(e14), "v"(e15));   \
        u32x2 s3_ = swap32v(d1, d3);                                           \
        u32x4 hi_; hi_[0] = s2_[0]; hi_[1] = s3_[0]; hi_[2] = s2_[1]; hi_[3] = s3_[1]; \
        PHI = __builtin_bit_cast(short8, hi_);                                 \
    }

#define PRODUCE(T)                                                             \
    {                                                                          \
        const int tn_ = ((T) + 1) & 63;                                        \
        const int pb_ = (T) & 1;                                               \
        __builtin_amdgcn_s_setprio(1);                                         \
        f32x16 dd0 = __builtin_amdgcn_mfma_f32_32x32x16_bf16(kf00, qf0, z16, 0, 0, 0); \
        dd0 = __builtin_amdgcn_mfma_f32_32x32x16_bf16(kf01, qf1, dd0, 0, 0, 0);\
        f32x16 dd1 = __builtin_amdgcn_mfma_f32_32x32x16_bf16(kf10, qf0, z16, 0, 0, 0); \
        dd1 = __builtin_amdgcn_mfma_f32_32x32x16_bf16(kf11, qf1, dd1, 0, 0, 0);\
        __builtin_amdgcn_s_setprio(0);                                         \
        kf00 = *(const short8*)(kfp + (size_t)(4 * tn_ + 0) * 512);            \
        kf01 = *(const short8*)(kfp + (size_t)(4 * tn_ + 1) * 512);            \
        kf10 = *(const short8*)(kfp + (size_t)(4 * tn_ + 2) * 512);            \
        kf11 = *(const short8*)(kfp + (size_t)(4 * tn_ + 3) * 512);            \
        short8 pa0, pa1, pa2, pa3;                                             \
        EXPPACK(dd0, pa0, pa1)                                                 \
        EXPPACK(dd1, pa2, pa3)                                                 \
        *(short8*)&p_lds[pb_][w][0][l][0] = pa0;                               \
        *(short8*)&p_lds[pb_][w][1][l][0] = pa1;                               \
        *(short8*)&p_lds[pb_][w][2][l][0] = pa2;                               \
        *(short8*)&p_lds[pb_][w][3][l][0] = pa3;                               \
    }

        PRODUCE(0)
        for (int t = 1; t < 64; ++t) {
            block_sync_lds();
            PRODUCE(t)
        }
        block_sync_lds();
#undef PRODUCE
#undef EXPPACK

        psum += __shfl_xor(psum, 32);
        if (l5 == 0) lsum_lds[32 * w + l31] = psum;
        __syncthreads();
    } else {
        // ================= CONSUMER: channels [32(w-4), +32) ================
        const int cw = w - 4;                 // 0..7
        const int ch = 32 * cw + l31;
        const unsigned short* vfp = vfrag + ((size_t)(b * 8 + cw) * 256) * 512 + 8 * l;

        f32x16 acc0 = (f32x16)0.0f, acc1 = (f32x16)0.0f;
        f32x16 acc2 = (f32x16)0.0f, acc3 = (f32x16)0.0f;
        // current-phase V set (tile 0) and next-phase set
        short8 vC0 = *(const short8*)(vfp + 0 * 512);
        short8 vC1 = *(const short8*)(vfp + 1 * 512);
        short8 vC2 = *(const short8*)(vfp + 2 * 512);
        short8 vC3 = *(const short8*)(vfp + 3 * 512);
        short8 vN0, vN1, vN2, vN3;

#define CKS(PB, KS, VF)                                                        \
        {                                                                      \
            short8 p0 = *(const short8*)&p_lds[PB][0][KS][l][0];               \
            short8 p1 = *(const short8*)&p_lds[PB][1][KS][l][0];               \
            short8 p2 = *(const short8*)&p_lds[PB][2][KS][l][0];               \
            short8 p3 = *(const short8*)&p_lds[PB][3][KS][l][0];               \
            acc0 = __builtin_amdgcn_mfma_f32_32x32x16_bf16(p0, VF, acc0, 0, 0, 0); \
            acc1 = __builtin_amdgcn_mfma_f32_32x32x16_bf16(p1, VF, acc1, 0, 0, 0); \
            acc2 = __builtin_amdgcn_mfma_f32_32x32x16_bf16(p2, VF, acc2, 0, 0, 0); \
            acc3 = __builtin_amdgcn_mfma_f32_32x32x16_bf16(p3, VF, acc3, 0, 0, 0); \
        }

// one phase: consume tile T with set (C0..C3); prefetch tile T+1 into (N0..N3)
#define CPHASE(T, C0, C1, C2, C3, N0, N1, N2, N3)                              \
        {                                                                      \
            block_sync_lds();                                                  \
            const int pb_ = (T) & 1;                                           \
            const int nf_ = 4 * (((T) + 1) & 63);                              \
            N0 = *(const short8*)(vfp + (size_t)(nf_ + 0) * 512);              \
            N1 = *(const short8*)(vfp + (size_t)(nf_ + 1) * 512);              \
            N2 = *(const short8*)(vfp + (size_t)(nf_ + 2) * 512);              \
            N3 = *(const short8*)(vfp + (size_t)(nf_ + 3) * 512);              \
            __builtin_amdgcn_s_setprio(1);                                     \
            CKS(pb_, 0, C0)                                                    \
            CKS(pb_, 1, C1)                                                    \
            CKS(pb_, 2, C2)                                                    \
            CKS(pb_, 3, C3)                                                    \
            __builtin_amdgcn_s_setprio(0);                                     \
        }

        for (int t = 0; t < 64; t += 2) {
            CPHASE(t,     vC0, vC1, vC2, vC3, vN0, vN1, vN2, vN3)
            CPHASE(t + 1, vN0, vN1, vN2, vN3, vC0, vC1, vC2, vC3)
        }
#undef CPHASE
#undef CKS
        __syncthreads();     // producers' lsum_lds writes now visible

        // ---- epilogue: out = gamma*acc/lsum + x ----
        const float g = gamma[0];
#pragma unroll
        for (int rq = 0; rq < 4; ++rq) {
            const int rbase = 8 * rq + 4 * l5;
#define STORE_QB(ACC, QB)                                                      \
            {                                                                  \
                f32x4 ls = *(const f32x4*)&lsum_lds[32 * (QB) + rbase];        \
                f32x4 gi;                                                      \
                gi[0] = g / ls[0]; gi[1] = g / ls[1];                          \
                gi[2] = g / ls[2]; gi[3] = g / ls[3];                          \
                size_t off = bx_base + (size_t)ch * 4096 + s0 + 32 * (QB) + rbase; \
                f32x4 xv = *(const f32x4*)(x + off);                           \
                f32x4 o;                                                       \
                o[0] = gi[0] * (ACC)[4 * rq + 0] + xv[0];                      \
                o[1] = gi[1] * (ACC)[4 * rq + 1] + xv[1];                      \
                o[2] = gi[2] * (ACC)[4 * rq + 2] + xv[2];                      \
                o[3] = gi[3] * (ACC)[4 * rq + 3] + xv[3];                      \
                *(f32x4*)(out + off) = o;                                      \
            }
            STORE_QB(acc0, 0)
            STORE_QB(acc1, 1)
            STORE_QB(acc2, 2)
            STORE_QB(acc3, 3)
#undef STORE_QB
        }
    }
}

// ---------------------------------------------------------------------------
extern "C" void kernel_launch(void* const* d_in, const int* in_sizes, int n_in,
                              void* d_out, int out_size, void* d_ws, size_t ws_size,
                              hipStream_t stream) {
    const float* x     = (const float*)d_in[0];
    const float* wqk   = (const float*)d_in[1];
    const float* wv    = (const float*)d_in[2];
    const float* gamma = (const float*)d_in[3];
    float* out = (float*)d_out;

    char* ws = (char*)d_ws;
    unsigned short* W     = (unsigned short*)(ws);                      // 160 KiB
    unsigned short* qkT   = (unsigned short*)(ws + 163840);             // 4 MiB
    unsigned short* xT    = (unsigned short*)(ws + 4358144);            // 16 MiB (-> vfrag)
    unsigned short* vbuf  = (unsigned short*)(ws + 21135360);           // 16 MiB
    unsigned short* kfrag = (unsigned short*)(ws + 37912576);           // 2 MiB
    unsigned short* vfrag = xT;   // reuse xT region (dead after proj)

    hipLaunchKernelGGL(prep_w_kernel,    dim3(320),  dim3(256), 0, stream, wqk, wv, W);
    hipLaunchKernelGGL(transpose_kernel, dim3(2048), dim3(256), 0, stream, x, xT);
    hipLaunchKernelGGL(proj_kernel,      dim3(512),  dim3(256), 0, stream, W, xT, qkT, vbuf);
    hipLaunchKernelGGL(repack_v_kernel,  dim3(4096), dim3(256), 0, stream, vbuf, vfrag);
    hipLaunchKernelGGL(repack_k_kernel,  dim3(512),  dim3(256), 0, stream, qkT, kfrag);
    hipLaunchKernelGGL(attn_kernel,      dim3(256),  dim3(768), 0, stream, qkT, kfrag, vfrag, x, gamma, out);
}

// Round 20
// 130.965 us; speedup vs baseline: 1.1284x; 1.0939x over previous
//
#include <hip/hip_runtime.h>

typedef __attribute__((ext_vector_type(4)))  float f32x4;
typedef __attribute__((ext_vector_type(16))) float f32x16;
typedef __attribute__((ext_vector_type(8)))  short short8;
typedef __attribute__((ext_vector_type(4)))  unsigned short u16x4;
typedef __attribute__((ext_vector_type(4)))  unsigned int u32x4;
typedef __attribute__((ext_vector_type(2)))  unsigned int u32x2;

// float -> bf16, round-to-nearest-even
static __device__ __forceinline__ unsigned short f2bf(float f) {
    unsigned int u = __float_as_uint(f);
    unsigned int r = (u + 0x7FFFu + ((u >> 16) & 1u)) >> 16;
    return (unsigned short)r;
}

#if __has_builtin(__builtin_amdgcn_exp2f)
#define EXP2(x) __builtin_amdgcn_exp2f(x)
#else
#define EXP2(x) exp2f(x)
#endif

static __device__ __forceinline__ u32x2 swap32v(unsigned int a, unsigned int b) {
#if __has_builtin(__builtin_amdgcn_permlane32_swap)
    return __builtin_amdgcn_permlane32_swap(a, b, false, false);
#else
    asm("v_permlane32_swap_b32 %0, %1" : "+v"(a), "+v"(b));
    u32x2 r; r[0] = a; r[1] = b; return r;
#endif
}

// lgkm-drain + raw barrier (vmcnt NOT drained: K/V prefetches stay in flight)
static __device__ __forceinline__ void block_sync_lds() {
    asm volatile("s_waitcnt lgkmcnt(0)" ::: "memory");
    __builtin_amdgcn_s_barrier();
    asm volatile("" ::: "memory");
}

// 32^-0.5 * log2(e)
#define SCALE2Q 0.25503487756f

// ---------------------------------------------------------------------------
__global__ void prep_w_kernel(const float* __restrict__ wqk,
                              const float* __restrict__ wv,
                              unsigned short* __restrict__ W) {
    int idx = blockIdx.x * 256 + threadIdx.x;
    int o = idx >> 8, c = idx & 255;
    float v;
    if (o < 64) { v = wqk[o * 256 + c]; if (o < 32) v *= SCALE2Q; }
    else        { v = wv[(o - 64) * 256 + c]; }
    W[idx] = f2bf(v);
}

// ---------------------------------------------------------------------------
__global__ __launch_bounds__(256) void transpose_kernel(
        const float* __restrict__ x, unsigned short* __restrict__ xT) {
    __shared__ unsigned short tile[64][66];
    int b = blockIdx.x & 7;
    int rem = blockIdx.x >> 3;
    int ct = rem >> 6, st = rem & 63;
    int s0 = st * 64, c0 = ct * 64;
    int tid = threadIdx.x;
    int ss = tid & 63, cq = tid >> 6;
#pragma unroll
    for (int p = 0; p < 16; ++p) {
        int cc = p * 4 + cq;
        float v = x[(size_t)(b * 256 + c0 + cc) * 4096 + s0 + ss];
        tile[ss][cc] = f2bf(v);
    }
    __syncthreads();
#pragma unroll
    for (int p = 0; p < 8; ++p) {
        int idx = p * 256 + tid;
        int sr = idx >> 5, jj = idx & 31;
        unsigned int val = *(const unsigned int*)&tile[sr][jj * 2];
        *(unsigned int*)(xT + (size_t)(b * 4096 + s0 + sr) * 256 + c0 + jj * 2) = val;
    }
}

// ---------------------------------------------------------------------------
// Kernel 3: projection GEMM (MFMA 16x16x32). Writes qkT directly and V via
// LDS staging in EXACT vfrag layout -> coalesced b128 vfrag stores.
// (Replaces the old scattered vbuf scalar stores + separate repack_v pass.)
// ---------------------------------------------------------------------------
__global__ __launch_bounds__(256) void proj_kernel(
        const unsigned short* __restrict__ W,     // [320][256]
        const unsigned short* __restrict__ xT,    // [8][4096][256]
        unsigned short* __restrict__ qkT,         // [8][4096][64]
        unsigned short* __restrict__ vfrag) {     // [8][8][256][64][8]
    __shared__ unsigned short vtile[8][4][64][8];  // 32 KiB, frag layout
    const int b  = blockIdx.x & 7;
    const int sb = blockIdx.x >> 3;     // 0..63
    const int s0 = sb * 64;
    const int tid = threadIdx.x;
    const int w = tid >> 6, l = tid & 63;
    const int lg = l >> 4, ll = l & 15;
    const size_t xbase = (size_t)b * 4096 * 256;

    f32x4 acc[5][4];
#pragma unroll
    for (int ot = 0; ot < 5; ++ot)
#pragma unroll
        for (int st = 0; st < 4; ++st) acc[ot][st] = (f32x4)0.0f;

    for (int k0 = 0; k0 < 256; k0 += 32) {
        short8 bf[4], af[5];
#pragma unroll
        for (int st = 0; st < 4; ++st)
            bf[st] = *(const short8*)(xT + xbase + (size_t)(s0 + st * 16 + ll) * 256 + k0 + lg * 8);
#pragma unroll
        for (int ot = 0; ot < 5; ++ot)
            af[ot] = *(const short8*)(W + (size_t)(80 * w + ot * 16 + ll) * 256 + k0 + lg * 8);
#pragma unroll
        for (int ot = 0; ot < 5; ++ot)
#pragma unroll
            for (int st = 0; st < 4; ++st)
                acc[ot][st] = __builtin_amdgcn_mfma_f32_16x16x32_bf16(af[ot], bf[st], acc[ot][st], 0, 0, 0);
    }
#pragma unroll
    for (int ot = 0; ot < 5; ++ot) {
        int o0 = 80 * w + ot * 16 + lg * 4;
#pragma unroll
        for (int st = 0; st < 4; ++st) {
            int sl = st * 16 + ll;              // block-local s
            if (o0 < 64) {
                u16x4 pk;
#pragma unroll
                for (int i = 0; i < 4; ++i) pk[i] = f2bf(acc[ot][st][i]);
                *(u16x4*)(qkT + (size_t)b * 4096 * 64 + (size_t)(s0 + sl) * 64 + o0) = pk;
            } else {
                // stage V into vtile in frag layout:
                // lane = (c&31) + 32*((sl>>3)&1), elem j = sl&7, chunk kf = sl>>4
#pragma unroll
                for (int i = 0; i < 4; ++i) {
                    int c = o0 - 64 + i;
                    vtile[c >> 5][sl >> 4][(c & 31) + 32 * ((sl >> 3) & 1)][sl & 7]
                        = f2bf(acc[ot][st][i]);
                }
            }
        }
    }
    __syncthreads();
    // coalesced vfrag writeout: wave wv handles kf16l = wv, each thread one
    // b128 per ct4. global kf16 = sb*4 + wv.
    const int wv = w;                            // 0..3 == kf16l
#pragma unroll
    for (int ct4 = 0; ct4 < 8; ++ct4) {
        short8 v = *(const short8*)&vtile[ct4][wv][l][0];
        *(short8*)(vfrag + ((size_t)((b * 8 + ct4) * 256) + sb * 4 + wv) * 512 + 8 * l) = v;
    }
}

// ---------------------------------------------------------------------------
__global__ __launch_bounds__(256) void repack_k_kernel(
        const unsigned short* __restrict__ qkT,    // [8][4096][64]
        unsigned short* __restrict__ kfrag) {      // [8][128][2][64][8]
    int idx = blockIdx.x * 256 + threadIdx.x;
    int l  = idx & 63;
    int h  = (idx >> 6) & 1;
    int t2 = (idx >> 7) & 127;
    int b  = idx >> 14;
    int l31 = l & 31, l5 = l >> 5;
    short8 v = *(const short8*)(qkT + (size_t)b * 4096 * 64
                                + (size_t)(32 * t2 + l31) * 64
                                + 32 + 16 * h + 8 * l5);
    *(short8*)(kfrag + (size_t)idx * 8) = v;
}

// ---------------------------------------------------------------------------
// Kernel 4: attention, P/C split, KVBLK=64, full-phase V prefetch + setprio.
// (unchanged from best-known R19 version, ~97 us)
// ---------------------------------------------------------------------------
__global__ __launch_bounds__(768, 3) void attn_kernel(
        const unsigned short* __restrict__ qkT,   // [8][4096][64] (q|k)
        const unsigned short* __restrict__ kfrag, // [8][128][2][64][8]
        const unsigned short* __restrict__ vfrag, // [8][8][256][64][8]
        const float* __restrict__ x,              // [8][256][4096]
        const float* __restrict__ gamma,
        float* __restrict__ out) {
    __shared__ unsigned short p_lds[2][4][4][64][8];  // 32 KiB [buf][qb][ks][lane][8]
    __shared__ float lsum_lds[128];

    const int b   = blockIdx.x & 7;          // batch == XCD (L2 pinning)
    const int sb  = blockIdx.x >> 3;         // 0..31
    const int s0  = sb * 128;
    const int w   = threadIdx.x >> 6;        // 0..11
    const int l   = threadIdx.x & 63;
    const int l5  = l >> 5, l31 = l & 31;

    const size_t qk_base = (size_t)b * 4096 * 64;
    const size_t bx_base = (size_t)b * 256 * 4096;

    if (w < 4) {
        // ================= PRODUCER: q-rows [s0+32w, +32) ===================
        const unsigned short* qrow = qkT + qk_base + (size_t)(s0 + 32 * w + l31) * 64;
        const short8 qf0 = *(const short8*)(qrow + 8 * l5);
        const short8 qf1 = *(const short8*)(qrow + 16 + 8 * l5);
        const unsigned short* kfp = kfrag + (size_t)b * 128 * 2 * 512 + 8 * l;
        const f32x16 z16 = (f32x16)0.0f;
        float psum = 0.f;

        short8 kf00 = *(const short8*)(kfp + 0 * 512);
        short8 kf01 = *(const short8*)(kfp + 1 * 512);
        short8 kf10 = *(const short8*)(kfp + 2 * 512);
        short8 kf11 = *(const short8*)(kfp + 3 * 512);

#define EXPPACK(DD, PLO, PHI)                                                  \
    {                                                                          \
        float e0 = EXP2((DD)[0]),   e1 = EXP2((DD)[1]);                        \
        float e2 = EXP2((DD)[2]),   e3 = EXP2((DD)[3]);                        \
        float e4 = EXP2((DD)[4]),   e5 = EXP2((DD)[5]);                        \
        float e6 = EXP2((DD)[6]),   e7 = EXP2((DD)[7]);                        \
        float e8 = EXP2((DD)[8]),   e9 = EXP2((DD)[9]);                        \
        float e10 = EXP2((DD)[10]), e11 = EXP2((DD)[11]);                      \
        float e12 = EXP2((DD)[12]), e13 = EXP2((DD)[13]);                      \
        float e14 = EXP2((DD)[14]), e15 = EXP2((DD)[15]);                      \
        psum += (((e0 + e1) + (e2 + e3)) + ((e4 + e5) + (e6 + e7)))            \
              + (((e8 + e9) + (e10 + e11)) + ((e12 + e13) + (e14 + e15)));     \
        unsigned int c0, c1, c2, c3;                                           \
        asm("v_cvt_pk_bf16_f32 %0, %1, %2" : "=v"(c0) : "v"(e0), "v"(e1));     \
        asm("v_cvt_pk_bf16_f32 %0, %1, %2" : "=v"(c1) : "v"(e2), "v"(e3));     \
        asm("v_cvt_pk_bf16_f32 %0, %1, %2" : "=v"(c2) : "v"(e4), "v"(e5));     \
        asm("v_cvt_pk_bf16_f32 %0, %1, %2" : "=v"(c3) : "v"(e6), "v"(e7));     \
        u32x2 s0_ = swap32v(c0, c2);                                           \
        u32x2 s1_ = swap32v(c1, c3);                                           \
        u32x4 lo_; lo_[0] = s0_[0]; lo_[1] = s1_[0]; lo_[2] = s0_[1]; lo_[3] = s1_[1]; \
        PLO = __builtin_bit_cast(short8, lo_);                                 \
        unsigned int d0, d1, d2, d3;                                           \
        asm("v_cvt_pk_bf16_f32 %0, %1, %2" : "=v"(d0) : "v"(e8), "v"(e9));     \
        asm("v_cvt_pk_bf16_f32 %0, %1, %2" : "=v"(d1) : "v"(e10), "v"(e11));   \
        asm("v_cvt_pk_bf16_f32 %0, %1, %2" : "=v"(d2) : "v"(e12), "v"(e13));   \
        u32x2 s2_ = swap32v(d0, d2);                                           \
        asm("v_cvt_pk_bf16_f32 %0, %1, %2" : "=v"(d3) : "v"(e14), "v"(e15));   \
        u32x2 s3_ = swap32v(d1, d3);                                           \
        u32x4 hi_; hi_[0] = s2_[0]; hi_[1] = s3_[0]; hi_[2] = s2_[1]; hi_[3] = s3_[1]; \
        PHI = __builtin_bit_cast(short8, hi_);                                 \
    }

#define PRODUCE(T)                                                             \
    {                                                                          \
        const int tn_ = ((T) + 1) & 63;                                        \
        const int pb_ = (T) & 1;                                               \
        __builtin_amdgcn_s_setprio(1);                                         \
        f32x16 dd0 = __builtin_amdgcn_mfma_f32_32x32x16_bf16(kf00, qf0, z16, 0, 0, 0); \
        dd0 = __builtin_amdgcn_mfma_f32_32x32x16_bf16(kf01, qf1, dd0, 0, 0, 0);\
        f32x16 dd1 = __builtin_amdgcn_mfma_f32_32x32x16_bf16(kf10, qf0, z16, 0, 0, 0); \
        dd1 = __builtin_amdgcn_mfma_f32_32x32x16_bf16(kf11, qf1, dd1, 0, 0, 0);\
        __builtin_amdgcn_s_setprio(0);                                         \
        kf00 = *(const short8*)(kfp + (size_t)(4 * tn_ + 0) * 512);            \
        kf01 = *(const short8*)(kfp + (size_t)(4 * tn_ + 1) * 512);            \
        kf10 = *(const short8*)(kfp + (size_t)(4 * tn_ + 2) * 512);            \
        kf11 = *(const short8*)(kfp + (size_t)(4 * tn_ + 3) * 512);            \
        short8 pa0, pa1, pa2, pa3;                                             \
        EXPPACK(dd0, pa0, pa1)                                                 \
        EXPPACK(dd1, pa2, pa3)                                                 \
        *(short8*)&p_lds[pb_][w][0][l][0] = pa0;                               \
        *(short8*)&p_lds[pb_][w][1][l][0] = pa1;                               \
        *(short8*)&p_lds[pb_][w][2][l][0] = pa2;                               \
        *(short8*)&p_lds[pb_][w][3][l][0] = pa3;                               \
    }

        PRODUCE(0)
        for (int t = 1; t < 64; ++t) {
            block_sync_lds();
            PRODUCE(t)
        }
        block_sync_lds();
#undef PRODUCE
#undef EXPPACK

        psum += __shfl_xor(psum, 32);
        if (l5 == 0) lsum_lds[32 * w + l31] = psum;
        __syncthreads();
    } else {
        // ================= CONSUMER: channels [32(w-4), +32) ================
        const int cw = w - 4;                 // 0..7
        const int ch = 32 * cw + l31;
        const unsigned short* vfp = vfrag + ((size_t)(b * 8 + cw) * 256) * 512 + 8 * l;

        f32x16 acc0 = (f32x16)0.0f, acc1 = (f32x16)0.0f;
        f32x16 acc2 = (f32x16)0.0f, acc3 = (f32x16)0.0f;
        short8 vC0 = *(const short8*)(vfp + 0 * 512);
        short8 vC1 = *(const short8*)(vfp + 1 * 512);
        short8 vC2 = *(const short8*)(vfp + 2 * 512);
        short8 vC3 = *(const short8*)(vfp + 3 * 512);
        short8 vN0, vN1, vN2, vN3;

#define CKS(PB, KS, VF)                                                        \
        {                                                                      \
            short8 p0 = *(const short8*)&p_lds[PB][0][KS][l][0];               \
            short8 p1 = *(const short8*)&p_lds[PB][1][KS][l][0];               \
            short8 p2 = *(const short8*)&p_lds[PB][2][KS][l][0];               \
            short8 p3 = *(const short8*)&p_lds[PB][3][KS][l][0];               \
            acc0 = __builtin_amdgcn_mfma_f32_32x32x16_bf16(p0, VF, acc0, 0, 0, 0); \
            acc1 = __builtin_amdgcn_mfma_f32_32x32x16_bf16(p1, VF, acc1, 0, 0, 0); \
            acc2 = __builtin_amdgcn_mfma_f32_32x32x16_bf16(p2, VF, acc2, 0, 0, 0); \
            acc3 = __builtin_amdgcn_mfma_f32_32x32x16_bf16(p3, VF, acc3, 0, 0, 0); \
        }

#define CPHASE(T, C0, C1, C2, C3, N0, N1, N2, N3)                              \
        {                                                                      \
            block_sync_lds();                                                  \
            const int pb_ = (T) & 1;                                           \
            const int nf_ = 4 * (((T) + 1) & 63);                              \
            N0 = *(const short8*)(vfp + (size_t)(nf_ + 0) * 512);              \
            N1 = *(const short8*)(vfp + (size_t)(nf_ + 1) * 512);              \
            N2 = *(const short8*)(vfp + (size_t)(nf_ + 2) * 512);              \
            N3 = *(const short8*)(vfp + (size_t)(nf_ + 3) * 512);              \
            __builtin_amdgcn_s_setprio(1);                                     \
            CKS(pb_, 0, C0)                                                    \
            CKS(pb_, 1, C1)                                                    \
            CKS(pb_, 2, C2)                                                    \
            CKS(pb_, 3, C3)                                                    \
            __builtin_amdgcn_s_setprio(0);                                     \
        }

        for (int t = 0; t < 64; t += 2) {
            CPHASE(t,     vC0, vC1, vC2, vC3, vN0, vN1, vN2, vN3)
            CPHASE(t + 1, vN0, vN1, vN2, vN3, vC0, vC1, vC2, vC3)
        }
#undef CPHASE
#undef CKS
        __syncthreads();     // producers' lsum_lds writes now visible

        const float g = gamma[0];
#pragma unroll
        for (int rq = 0; rq < 4; ++rq) {
            const int rbase = 8 * rq + 4 * l5;
#define STORE_QB(ACC, QB)                                                      \
            {                                                                  \
                f32x4 ls = *(const f32x4*)&lsum_lds[32 * (QB) + rbase];        \
                f32x4 gi;                                                      \
                gi[0] = g / ls[0]; gi[1] = g / ls[1];                          \
                gi[2] = g / ls[2]; gi[3] = g / ls[3];                          \
                size_t off = bx_base + (size_t)ch * 4096 + s0 + 32 * (QB) + rbase; \
                f32x4 xv = *(const f32x4*)(x + off);                           \
                f32x4 o;                                                       \
                o[0] = gi[0] * (ACC)[4 * rq + 0] + xv[0];                      \
                o[1] = gi[1] * (ACC)[4 * rq + 1] + xv[1];                      \
                o[2] = gi[2] * (ACC)[4 * rq + 2] + xv[2];                      \
                o[3] = gi[3] * (ACC)[4 * rq + 3] + xv[3];                      \
                *(f32x4*)(out + off) = o;                                      \
            }
            STORE_QB(acc0, 0)
            STORE_QB(acc1, 1)
            STORE_QB(acc2, 2)
            STORE_QB(acc3, 3)
#undef STORE_QB
        }
    }
}

// ---------------------------------------------------------------------------
extern "C" void kernel_launch(void* const* d_in, const int* in_sizes, int n_in,
                              void* d_out, int out_size, void* d_ws, size_t ws_size,
                              hipStream_t stream) {
    const float* x     = (const float*)d_in[0];
    const float* wqk   = (const float*)d_in[1];
    const float* wv    = (const float*)d_in[2];
    const float* gamma = (const float*)d_in[3];
    float* out = (float*)d_out;

    char* ws = (char*)d_ws;
    unsigned short* W     = (unsigned short*)(ws);                      // 160 KiB
    unsigned short* qkT   = (unsigned short*)(ws + 163840);             // 4 MiB
    unsigned short* xT    = (unsigned short*)(ws + 4358144);            // 16 MiB
    unsigned short* vfrag = (unsigned short*)(ws + 21135360);           // 16 MiB
    unsigned short* kfrag = (unsigned short*)(ws + 37912576);           // 2 MiB

    hipLaunchKernelGGL(prep_w_kernel,    dim3(320),  dim3(256), 0, stream, wqk, wv, W);
    hipLaunchKernelGGL(transpose_kernel, dim3(2048), dim3(256), 0, stream, x, xT);
    hipLaunchKernelGGL(proj_kernel,      dim3(512),  dim3(256), 0, stream, W, xT, qkT, vfrag);
    hipLaunchKernelGGL(repack_k_kernel,  dim3(512),  dim3(256), 0, stream, qkT, kfrag);
    hipLaunchKernelGGL(attn_kernel,      dim3(256),  dim3(768), 0, stream, qkT, kfrag, vfrag, x, gamma, out);
}

// Round 21
// 128.603 us; speedup vs baseline: 1.1491x; 1.0184x over previous
//
#include <hip/hip_runtime.h>

typedef __attribute__((ext_vector_type(4)))  float f32x4;
typedef __attribute__((ext_vector_type(16))) float f32x16;
typedef __attribute__((ext_vector_type(8)))  short short8;
typedef __attribute__((ext_vector_type(4)))  unsigned short u16x4;
typedef __attribute__((ext_vector_type(4)))  unsigned int u32x4;
typedef __attribute__((ext_vector_type(2)))  unsigned int u32x2;

// float -> bf16, round-to-nearest-even
static __device__ __forceinline__ unsigned short f2bf(float f) {
    unsigned int u = __float_as_uint(f);
    unsigned int r = (u + 0x7FFFu + ((u >> 16) & 1u)) >> 16;
    return (unsigned short)r;
}

#if __has_builtin(__builtin_amdgcn_exp2f)
#define EXP2(x) __builtin_amdgcn_exp2f(x)
#else
#define EXP2(x) exp2f(x)
#endif

static __device__ __forceinline__ u32x2 swap32v(unsigned int a, unsigned int b) {
#if __has_builtin(__builtin_amdgcn_permlane32_swap)
    return __builtin_amdgcn_permlane32_swap(a, b, false, false);
#else
    asm("v_permlane32_swap_b32 %0, %1" : "+v"(a), "+v"(b));
    u32x2 r; r[0] = a; r[1] = b; return r;
#endif
}

// lgkm-drain + raw barrier (vmcnt NOT drained: K/V prefetches stay in flight)
static __device__ __forceinline__ void block_sync_lds() {
    asm volatile("s_waitcnt lgkmcnt(0)" ::: "memory");
    __builtin_amdgcn_s_barrier();
    asm volatile("" ::: "memory");
}

// 32^-0.5 * log2(e)
#define SCALE2Q 0.25503487756f

// ---------------------------------------------------------------------------
__global__ void prep_w_kernel(const float* __restrict__ wqk,
                              const float* __restrict__ wv,
                              unsigned short* __restrict__ W) {
    int idx = blockIdx.x * 256 + threadIdx.x;
    int o = idx >> 8, c = idx & 255;
    float v;
    if (o < 64) { v = wqk[o * 256 + c]; if (o < 32) v *= SCALE2Q; }
    else        { v = wv[(o - 64) * 256 + c]; }
    W[idx] = f2bf(v);
}

// ---------------------------------------------------------------------------
__global__ __launch_bounds__(256) void transpose_kernel(
        const float* __restrict__ x, unsigned short* __restrict__ xT) {
    __shared__ unsigned short tile[64][66];
    int b = blockIdx.x & 7;
    int rem = blockIdx.x >> 3;
    int ct = rem >> 6, st = rem & 63;
    int s0 = st * 64, c0 = ct * 64;
    int tid = threadIdx.x;
    int ss = tid & 63, cq = tid >> 6;
#pragma unroll
    for (int p = 0; p < 16; ++p) {
        int cc = p * 4 + cq;
        float v = x[(size_t)(b * 256 + c0 + cc) * 4096 + s0 + ss];
        tile[ss][cc] = f2bf(v);
    }
    __syncthreads();
#pragma unroll
    for (int p = 0; p < 8; ++p) {
        int idx = p * 256 + tid;
        int sr = idx >> 5, jj = idx & 31;
        unsigned int val = *(const unsigned int*)&tile[sr][jj * 2];
        *(unsigned int*)(xT + (size_t)(b * 4096 + s0 + sr) * 256 + c0 + jj * 2) = val;
    }
}

// ---------------------------------------------------------------------------
// Kernel 3: projection GEMM; writes qkT + vfrag (LDS-staged frag layout).
// ---------------------------------------------------------------------------
__global__ __launch_bounds__(256) void proj_kernel(
        const unsigned short* __restrict__ W,     // [320][256]
        const unsigned short* __restrict__ xT,    // [8][4096][256]
        unsigned short* __restrict__ qkT,         // [8][4096][64]
        unsigned short* __restrict__ vfrag) {     // [8][8][256][64][8]
    __shared__ unsigned short vtile[8][4][64][8];  // 32 KiB, frag layout
    const int b  = blockIdx.x & 7;
    const int sb = blockIdx.x >> 3;     // 0..63
    const int s0 = sb * 64;
    const int tid = threadIdx.x;
    const int w = tid >> 6, l = tid & 63;
    const int lg = l >> 4, ll = l & 15;
    const size_t xbase = (size_t)b * 4096 * 256;

    f32x4 acc[5][4];
#pragma unroll
    for (int ot = 0; ot < 5; ++ot)
#pragma unroll
        for (int st = 0; st < 4; ++st) acc[ot][st] = (f32x4)0.0f;

    for (int k0 = 0; k0 < 256; k0 += 32) {
        short8 bf[4], af[5];
#pragma unroll
        for (int st = 0; st < 4; ++st)
            bf[st] = *(const short8*)(xT + xbase + (size_t)(s0 + st * 16 + ll) * 256 + k0 + lg * 8);
#pragma unroll
        for (int ot = 0; ot < 5; ++ot)
            af[ot] = *(const short8*)(W + (size_t)(80 * w + ot * 16 + ll) * 256 + k0 + lg * 8);
#pragma unroll
        for (int ot = 0; ot < 5; ++ot)
#pragma unroll
            for (int st = 0; st < 4; ++st)
                acc[ot][st] = __builtin_amdgcn_mfma_f32_16x16x32_bf16(af[ot], bf[st], acc[ot][st], 0, 0, 0);
    }
#pragma unroll
    for (int ot = 0; ot < 5; ++ot) {
        int o0 = 80 * w + ot * 16 + lg * 4;
#pragma unroll
        for (int st = 0; st < 4; ++st) {
            int sl = st * 16 + ll;              // block-local s
            if (o0 < 64) {
                u16x4 pk;
#pragma unroll
                for (int i = 0; i < 4; ++i) pk[i] = f2bf(acc[ot][st][i]);
                *(u16x4*)(qkT + (size_t)b * 4096 * 64 + (size_t)(s0 + sl) * 64 + o0) = pk;
            } else {
#pragma unroll
                for (int i = 0; i < 4; ++i) {
                    int c = o0 - 64 + i;
                    vtile[c >> 5][sl >> 4][(c & 31) + 32 * ((sl >> 3) & 1)][sl & 7]
                        = f2bf(acc[ot][st][i]);
                }
            }
        }
    }
    __syncthreads();
    const int wv = w;                            // 0..3 == kf16l
#pragma unroll
    for (int ct4 = 0; ct4 < 8; ++ct4) {
        short8 v = *(const short8*)&vtile[ct4][wv][l][0];
        *(short8*)(vfrag + ((size_t)((b * 8 + ct4) * 256) + sb * 4 + wv) * 512 + 8 * l) = v;
    }
}

// ---------------------------------------------------------------------------
__global__ __launch_bounds__(256) void repack_k_kernel(
        const unsigned short* __restrict__ qkT,    // [8][4096][64]
        unsigned short* __restrict__ kfrag) {      // [8][128][2][64][8]
    int idx = blockIdx.x * 256 + threadIdx.x;
    int l  = idx & 63;
    int h  = (idx >> 6) & 1;
    int t2 = (idx >> 7) & 127;
    int b  = idx >> 14;
    int l31 = l & 31, l5 = l >> 5;
    short8 v = *(const short8*)(qkT + (size_t)b * 4096 * 64
                                + (size_t)(32 * t2 + l31) * 64
                                + 32 + 16 * h + 8 * l5);
    *(short8*)(kfrag + (size_t)idx * 8) = v;
}

// ---------------------------------------------------------------------------
// Kernel 4: attention, P/C split, 2 INDEPENDENT blocks/CU. Block = 64 q x
// 256 ch, 384 thr = 6 waves (2 producers + 4 consumers). Grid 512 =
// 8 b x 64 q-tiles => 2 blocks/CU, independent barrier domains: one block's
// rendezvous stall is filled by the other's work. Producers (32 q each):
// coalesced kfrag -> swapped QK (setprio'd) -> exp2 -> cvt_pk+permlane ->
// 4x ds_write_b128. Consumers (64 ch each = 2 ct-tiles x 2 q-blocks):
// 8x ds_read_b128 + 16 MFMA per phase (setprio'd), 2-slot rolling V.
// ---------------------------------------------------------------------------
__global__ __launch_bounds__(384, 3) void attn_kernel(
        const unsigned short* __restrict__ qkT,   // [8][4096][64] (q|k)
        const unsigned short* __restrict__ kfrag, // [8][128][2][64][8]
        const unsigned short* __restrict__ vfrag, // [8][8][256][64][8]
        const float* __restrict__ x,              // [8][256][4096]
        const float* __restrict__ gamma,
        float* __restrict__ out) {
    __shared__ unsigned short p_lds[2][2][4][64][8];  // 16 KiB [buf][qb][ks][lane][8]
    __shared__ float lsum_lds[64];

    const int b   = blockIdx.x & 7;          // batch == XCD (L2 pinning)
    const int sb  = blockIdx.x >> 3;         // 0..63
    const int s0  = sb * 64;
    const int w   = threadIdx.x >> 6;        // 0..5
    const int l   = threadIdx.x & 63;
    const int l5  = l >> 5, l31 = l & 31;

    const size_t qk_base = (size_t)b * 4096 * 64;
    const size_t bx_base = (size_t)b * 256 * 4096;

    if (w < 2) {
        // ================= PRODUCER: q-rows [s0+32w, +32) ===================
        const unsigned short* qrow = qkT + qk_base + (size_t)(s0 + 32 * w + l31) * 64;
        const short8 qf0 = *(const short8*)(qrow + 8 * l5);
        const short8 qf1 = *(const short8*)(qrow + 16 + 8 * l5);
        const unsigned short* kfp = kfrag + (size_t)b * 128 * 2 * 512 + 8 * l;
        const f32x16 z16 = (f32x16)0.0f;
        float psum = 0.f;

        short8 kf00 = *(const short8*)(kfp + 0 * 512);
        short8 kf01 = *(const short8*)(kfp + 1 * 512);
        short8 kf10 = *(const short8*)(kfp + 2 * 512);
        short8 kf11 = *(const short8*)(kfp + 3 * 512);

#define EXPPACK(DD, PLO, PHI)                                                  \
    {                                                                          \
        float e0 = EXP2((DD)[0]),   e1 = EXP2((DD)[1]);                        \
        float e2 = EXP2((DD)[2]),   e3 = EXP2((DD)[3]);                        \
        float e4 = EXP2((DD)[4]),   e5 = EXP2((DD)[5]);                        \
        float e6 = EXP2((DD)[6]),   e7 = EXP2((DD)[7]);                        \
        float e8 = EXP2((DD)[8]),   e9 = EXP2((DD)[9]);                        \
        float e10 = EXP2((DD)[10]), e11 = EXP2((DD)[11]);                      \
        float e12 = EXP2((DD)[12]), e13 = EXP2((DD)[13]);                      \
        float e14 = EXP2((DD)[14]), e15 = EXP2((DD)[15]);                      \
        psum += (((e0 + e1) + (e2 + e3)) + ((e4 + e5) + (e6 + e7)))            \
              + (((e8 + e9) + (e10 + e11)) + ((e12 + e13) + (e14 + e15)));     \
        unsigned int c0, c1, c2, c3;                                           \
        asm("v_cvt_pk_bf16_f32 %0, %1, %2" : "=v"(c0) : "v"(e0), "v"(e1));     \
        asm("v_cvt_pk_bf16_f32 %0, %1, %2" : "=v"(c1) : "v"(e2), "v"(e3));     \
        asm("v_cvt_pk_bf16_f32 %0, %1, %2" : "=v"(c2) : "v"(e4), "v"(e5));     \
        asm("v_cvt_pk_bf16_f32 %0, %1, %2" : "=v"(c3) : "v"(e6), "v"(e7));     \
        u32x2 s0_ = swap32v(c0, c2);                                           \
        u32x2 s1_ = swap32v(c1, c3);                                           \
        u32x4 lo_; lo_[0] = s0_[0]; lo_[1] = s1_[0]; lo_[2] = s0_[1]; lo_[3] = s1_[1]; \
        PLO = __builtin_bit_cast(short8, lo_);                                 \
        unsigned int d0, d1, d2, d3;                                           \
        asm("v_cvt_pk_bf16_f32 %0, %1, %2" : "=v"(d0) : "v"(e8), "v"(e9));     \
        asm("v_cvt_pk_bf16_f32 %0, %1, %2" : "=v"(d1) : "v"(e10), "v"(e11));   \
        asm("v_cvt_pk_bf16_f32 %0, %1, %2" : "=v"(d2) : "v"(e12), "v"(e13));   \
        u32x2 s2_ = swap32v(d0, d2);                                           \
        asm("v_cvt_pk_bf16_f32 %0, %1, %2" : "=v"(d3) : "v"(e14), "v"(e15));   \
        u32x2 s3_ = swap32v(d1, d3);                                           \
        u32x4 hi_; hi_[0] = s2_[0]; hi_[1] = s3_[0]; hi_[2] = s2_[1]; hi_[3] = s3_[1]; \
        PHI = __builtin_bit_cast(short8, hi_);                                 \
    }

#define PRODUCE(T)                                                             \
    {                                                                          \
        const int tn_ = ((T) + 1) & 63;                                        \
        const int pb_ = (T) & 1;                                               \
        __builtin_amdgcn_s_setprio(1);                                         \
        f32x16 dd0 = __builtin_amdgcn_mfma_f32_32x32x16_bf16(kf00, qf0, z16, 0, 0, 0); \
        dd0 = __builtin_amdgcn_mfma_f32_32x32x16_bf16(kf01, qf1, dd0, 0, 0, 0);\
        f32x16 dd1 = __builtin_amdgcn_mfma_f32_32x32x16_bf16(kf10, qf0, z16, 0, 0, 0); \
        dd1 = __builtin_amdgcn_mfma_f32_32x32x16_bf16(kf11, qf1, dd1, 0, 0, 0);\
        __builtin_amdgcn_s_setprio(0);                                         \
        kf00 = *(const short8*)(kfp + (size_t)(4 * tn_ + 0) * 512);            \
        kf01 = *(const short8*)(kfp + (size_t)(4 * tn_ + 1) * 512);            \
        kf10 = *(const short8*)(kfp + (size_t)(4 * tn_ + 2) * 512);            \
        kf11 = *(const short8*)(kfp + (size_t)(4 * tn_ + 3) * 512);            \
        short8 pa0, pa1, pa2, pa3;                                             \
        EXPPACK(dd0, pa0, pa1)                                                 \
        EXPPACK(dd1, pa2, pa3)                                                 \
        *(short8*)&p_lds[pb_][w][0][l][0] = pa0;                               \
        *(short8*)&p_lds[pb_][w][1][l][0] = pa1;                               \
        *(short8*)&p_lds[pb_][w][2][l][0] = pa2;                               \
        *(short8*)&p_lds[pb_][w][3][l][0] = pa3;                               \
    }

        PRODUCE(0)
        for (int t = 1; t < 64; ++t) {
            block_sync_lds();
            PRODUCE(t)
        }
        block_sync_lds();
#undef PRODUCE
#undef EXPPACK

        psum += __shfl_xor(psum, 32);
        if (l5 == 0) lsum_lds[32 * w + l31] = psum;
        __syncthreads();
    } else {
        // ================= CONSUMER: channels [64(w-2), +64) ================
        const int cw = w - 2;                 // 0..3
        const int ct0 = 2 * cw, ct1 = 2 * cw + 1;
        const unsigned short* vfp0 = vfrag + ((size_t)(b * 8 + ct0) * 256) * 512 + 8 * l;
        const unsigned short* vfp1 = vfrag + ((size_t)(b * 8 + ct1) * 256) * 512 + 8 * l;

        // acc[qb][ct]: 4 x f32x16 = 64 AGPR
        f32x16 a00 = (f32x16)0.0f, a10 = (f32x16)0.0f;   // ct0: qb0, qb1
        f32x16 a01 = (f32x16)0.0f, a11 = (f32x16)0.0f;   // ct1: qb0, qb1
        // 2-slot rolling V per ct
        short8 vA0 = *(const short8*)(vfp0 + 0 * 512);
        short8 vA1 = *(const short8*)(vfp1 + 0 * 512);
        short8 vB0 = *(const short8*)(vfp0 + 1 * 512);
        short8 vB1 = *(const short8*)(vfp1 + 1 * 512);

#define CKS(PB, KS, V0, V1)                                                    \
        {                                                                      \
            short8 p0 = *(const short8*)&p_lds[PB][0][KS][l][0];               \
            short8 p1 = *(const short8*)&p_lds[PB][1][KS][l][0];               \
            a00 = __builtin_amdgcn_mfma_f32_32x32x16_bf16(p0, V0, a00, 0, 0, 0); \
            a10 = __builtin_amdgcn_mfma_f32_32x32x16_bf16(p1, V0, a10, 0, 0, 0); \
            a01 = __builtin_amdgcn_mfma_f32_32x32x16_bf16(p0, V1, a01, 0, 0, 0); \
            a11 = __builtin_amdgcn_mfma_f32_32x32x16_bf16(p1, V1, a11, 0, 0, 0); \
        }

        for (int t = 0; t < 64; ++t) {
            block_sync_lds();
            const int pb = t & 1;
            const int tn = (t + 1) & 63;
            __builtin_amdgcn_s_setprio(1);
            CKS(pb, 0, vA0, vA1)
            __builtin_amdgcn_s_setprio(0);
            vA0 = *(const short8*)(vfp0 + (size_t)(4 * t + 2) * 512);
            vA1 = *(const short8*)(vfp1 + (size_t)(4 * t + 2) * 512);
            __builtin_amdgcn_s_setprio(1);
            CKS(pb, 1, vB0, vB1)
            __builtin_amdgcn_s_setprio(0);
            vB0 = *(const short8*)(vfp0 + (size_t)(4 * t + 3) * 512);
            vB1 = *(const short8*)(vfp1 + (size_t)(4 * t + 3) * 512);
            __builtin_amdgcn_s_setprio(1);
            CKS(pb, 2, vA0, vA1)
            __builtin_amdgcn_s_setprio(0);
            vA0 = *(const short8*)(vfp0 + (size_t)(4 * tn + 0) * 512);
            vA1 = *(const short8*)(vfp1 + (size_t)(4 * tn + 0) * 512);
            __builtin_amdgcn_s_setprio(1);
            CKS(pb, 3, vB0, vB1)
            __builtin_amdgcn_s_setprio(0);
            vB0 = *(const short8*)(vfp0 + (size_t)(4 * tn + 1) * 512);
            vB1 = *(const short8*)(vfp1 + (size_t)(4 * tn + 1) * 512);
        }
#undef CKS
        __syncthreads();     // producers' lsum_lds writes now visible

        // ---- epilogue: out = gamma*acc/lsum + x ----
        const float g = gamma[0];
#pragma unroll
        for (int rq = 0; rq < 4; ++rq) {
            const int rbase = 8 * rq + 4 * l5;
#define STORE_QB(ACC, QB, CT)                                                  \
            {                                                                  \
                f32x4 ls = *(const f32x4*)&lsum_lds[32 * (QB) + rbase];        \
                f32x4 gi;                                                      \
                gi[0] = g / ls[0]; gi[1] = g / ls[1];                          \
                gi[2] = g / ls[2]; gi[3] = g / ls[3];                          \
                size_t off = bx_base + (size_t)(32 * (CT) + l31) * 4096 + s0 + 32 * (QB) + rbase; \
                f32x4 xv = *(const f32x4*)(x + off);                           \
                f32x4 o;                                                       \
                o[0] = gi[0] * (ACC)[4 * rq + 0] + xv[0];                      \
                o[1] = gi[1] * (ACC)[4 * rq + 1] + xv[1];                      \
                o[2] = gi[2] * (ACC)[4 * rq + 2] + xv[2];                      \
                o[3] = gi[3] * (ACC)[4 * rq + 3] + xv[3];                      \
                *(f32x4*)(out + off) = o;                                      \
            }
            STORE_QB(a00, 0, ct0)
            STORE_QB(a10, 1, ct0)
            STORE_QB(a01, 0, ct1)
            STORE_QB(a11, 1, ct1)
#undef STORE_QB
        }
    }
}

// ---------------------------------------------------------------------------
extern "C" void kernel_launch(void* const* d_in, const int* in_sizes, int n_in,
                              void* d_out, int out_size, void* d_ws, size_t ws_size,
                              hipStream_t stream) {
    const float* x     = (const float*)d_in[0];
    const float* wqk   = (const float*)d_in[1];
    const float* wv    = (const float*)d_in[2];
    const float* gamma = (const float*)d_in[3];
    float* out = (float*)d_out;

    char* ws = (char*)d_ws;
    unsigned short* W     = (unsigned short*)(ws);                      // 160 KiB
    unsigned short* qkT   = (unsigned short*)(ws + 163840);             // 4 MiB
    unsigned short* xT    = (unsigned short*)(ws + 4358144);            // 16 MiB
    unsigned short* vfrag = (unsigned short*)(ws + 21135360);           // 16 MiB
    unsigned short* kfrag = (unsigned short*)(ws + 37912576);           // 2 MiB

    hipLaunchKernelGGL(prep_w_kernel,    dim3(320),  dim3(256), 0, stream, wqk, wv, W);
    hipLaunchKernelGGL(transpose_kernel, dim3(2048), dim3(256), 0, stream, x, xT);
    hipLaunchKernelGGL(proj_kernel,      dim3(512),  dim3(256), 0, stream, W, xT, qkT, vfrag);
    hipLaunchKernelGGL(repack_k_kernel,  dim3(512),  dim3(256), 0, stream, qkT, kfrag);
    hipLaunchKernelGGL(attn_kernel,      dim3(512),  dim3(384), 0, stream, qkT, kfrag, vfrag, x, gamma, out);
}

// Round 22
// 121.638 us; speedup vs baseline: 1.2149x; 1.0573x over previous
//
#include <hip/hip_runtime.h>

typedef __attribute__((ext_vector_type(4)))  float f32x4;
typedef __attribute__((ext_vector_type(16))) float f32x16;
typedef __attribute__((ext_vector_type(8)))  short short8;
typedef __attribute__((ext_vector_type(4)))  unsigned short u16x4;
typedef __attribute__((ext_vector_type(4)))  unsigned int u32x4;
typedef __attribute__((ext_vector_type(2)))  unsigned int u32x2;

// float -> bf16, round-to-nearest-even
static __device__ __forceinline__ unsigned short f2bf(float f) {
    unsigned int u = __float_as_uint(f);
    unsigned int r = (u + 0x7FFFu + ((u >> 16) & 1u)) >> 16;
    return (unsigned short)r;
}

#if __has_builtin(__builtin_amdgcn_exp2f)
#define EXP2(x) __builtin_amdgcn_exp2f(x)
#else
#define EXP2(x) exp2f(x)
#endif

static __device__ __forceinline__ u32x2 swap32v(unsigned int a, unsigned int b) {
#if __has_builtin(__builtin_amdgcn_permlane32_swap)
    return __builtin_amdgcn_permlane32_swap(a, b, false, false);
#else
    asm("v_permlane32_swap_b32 %0, %1" : "+v"(a), "+v"(b));
    u32x2 r; r[0] = a; r[1] = b; return r;
#endif
}

// lgkm-drain + raw barrier (vmcnt NOT drained: K/V prefetches stay in flight)
static __device__ __forceinline__ void block_sync_lds() {
    asm volatile("s_waitcnt lgkmcnt(0)" ::: "memory");
    __builtin_amdgcn_s_barrier();
    asm volatile("" ::: "memory");
}

// 32^-0.5 * log2(e)
#define SCALE2Q 0.25503487756f

// ---------------------------------------------------------------------------
// Kernel A: transpose (blocks 0..2047) + weight prep (blocks 2048..2367).
// ---------------------------------------------------------------------------
__global__ __launch_bounds__(256) void transpose_prep_kernel(
        const float* __restrict__ x, unsigned short* __restrict__ xT,
        const float* __restrict__ wqk, const float* __restrict__ wv,
        unsigned short* __restrict__ W) {
    if (blockIdx.x >= 2048) {
        // ---- weight pack: W[320][256] ----
        int idx = (blockIdx.x - 2048) * 256 + threadIdx.x;
        int o = idx >> 8, c = idx & 255;
        float v;
        if (o < 64) { v = wqk[o * 256 + c]; if (o < 32) v *= SCALE2Q; }
        else        { v = wv[(o - 64) * 256 + c]; }
        W[idx] = f2bf(v);
        return;
    }
    __shared__ unsigned short tile[64][66];
    int b = blockIdx.x & 7;
    int rem = blockIdx.x >> 3;
    int ct = rem >> 6, st = rem & 63;
    int s0 = st * 64, c0 = ct * 64;
    int tid = threadIdx.x;
    int ss = tid & 63, cq = tid >> 6;
#pragma unroll
    for (int p = 0; p < 16; ++p) {
        int cc = p * 4 + cq;
        float v = x[(size_t)(b * 256 + c0 + cc) * 4096 + s0 + ss];
        tile[ss][cc] = f2bf(v);
    }
    __syncthreads();
#pragma unroll
    for (int p = 0; p < 8; ++p) {
        int idx = p * 256 + tid;
        int sr = idx >> 5, jj = idx & 31;
        unsigned int val = *(const unsigned int*)&tile[sr][jj * 2];
        *(unsigned int*)(xT + (size_t)(b * 4096 + s0 + sr) * 256 + c0 + jj * 2) = val;
    }
}

// ---------------------------------------------------------------------------
// Kernel B: projection GEMM; writes qkT(q-half), kfrag and vfrag directly
// (k/V staged in LDS in exact frag layouts -> coalesced b128 stores).
// ---------------------------------------------------------------------------
__global__ __launch_bounds__(256) void proj_kernel(
        const unsigned short* __restrict__ W,     // [320][256]
        const unsigned short* __restrict__ xT,    // [8][4096][256]
        unsigned short* __restrict__ qkT,         // [8][4096][64] (q in 0..31)
        unsigned short* __restrict__ kfrag,       // [8][128][2][64][8]
        unsigned short* __restrict__ vfrag) {     // [8][8][256][64][8]
    __shared__ unsigned short vtile[8][4][64][8];  // 32 KiB, V frag layout
    __shared__ unsigned short kstage[64][40];      // 5 KiB, key x kchan (pad 40)
    const int b  = blockIdx.x & 7;
    const int sb = blockIdx.x >> 3;     // 0..63
    const int s0 = sb * 64;
    const int tid = threadIdx.x;
    const int w = tid >> 6, l = tid & 63;
    const int lg = l >> 4, ll = l & 15;
    const int l5 = l >> 5, l31 = l & 31;
    const size_t xbase = (size_t)b * 4096 * 256;

    f32x4 acc[5][4];
#pragma unroll
    for (int ot = 0; ot < 5; ++ot)
#pragma unroll
        for (int st = 0; st < 4; ++st) acc[ot][st] = (f32x4)0.0f;

    for (int k0 = 0; k0 < 256; k0 += 32) {
        short8 bf[4], af[5];
#pragma unroll
        for (int st = 0; st < 4; ++st)
            bf[st] = *(const short8*)(xT + xbase + (size_t)(s0 + st * 16 + ll) * 256 + k0 + lg * 8);
#pragma unroll
        for (int ot = 0; ot < 5; ++ot)
            af[ot] = *(const short8*)(W + (size_t)(80 * w + ot * 16 + ll) * 256 + k0 + lg * 8);
#pragma unroll
        for (int ot = 0; ot < 5; ++ot)
#pragma unroll
            for (int st = 0; st < 4; ++st)
                acc[ot][st] = __builtin_amdgcn_mfma_f32_16x16x32_bf16(af[ot], bf[st], acc[ot][st], 0, 0, 0);
    }
#pragma unroll
    for (int ot = 0; ot < 5; ++ot) {
        int o0 = 80 * w + ot * 16 + lg * 4;
#pragma unroll
        for (int st = 0; st < 4; ++st) {
            int sl = st * 16 + ll;              // block-local s (key)
            if (o0 < 32) {
                // q-half -> qkT directly
                u16x4 pk;
#pragma unroll
                for (int i = 0; i < 4; ++i) pk[i] = f2bf(acc[ot][st][i]);
                *(u16x4*)(qkT + (size_t)b * 4096 * 64 + (size_t)(s0 + sl) * 64 + o0) = pk;
            } else if (o0 < 64) {
                // k-half -> kstage[key][kchan]
                u16x4 pk;
#pragma unroll
                for (int i = 0; i < 4; ++i) pk[i] = f2bf(acc[ot][st][i]);
                *(u16x4*)&kstage[sl][o0 - 32] = pk;
            } else {
                // V -> vtile in frag layout
#pragma unroll
                for (int i = 0; i < 4; ++i) {
                    int c = o0 - 64 + i;
                    vtile[c >> 5][sl >> 4][(c & 31) + 32 * ((sl >> 3) & 1)][sl & 7]
                        = f2bf(acc[ot][st][i]);
                }
            }
        }
    }
    __syncthreads();
    // vfrag writeout (all 4 waves): global kf16 = sb*4 + w
#pragma unroll
    for (int ct4 = 0; ct4 < 8; ++ct4) {
        short8 v = *(const short8*)&vtile[ct4][w][l][0];
        *(short8*)(vfrag + ((size_t)((b * 8 + ct4) * 256) + sb * 4 + w) * 512 + 8 * l) = v;
    }
    // kfrag writeout (waves 0-1): tile t2 = sb*2 + w, h = 0,1
    if (w < 2) {
#pragma unroll
        for (int h = 0; h < 2; ++h) {
            short8 v = *(const short8*)&kstage[32 * w + l31][16 * h + 8 * l5];
            *(short8*)(kfrag + ((size_t)(b * 128 + sb * 2 + w) * 2 + h) * 512 + 8 * l) = v;
        }
    }
}

// ---------------------------------------------------------------------------
// Kernel C: attention, P/C split, 2 independent blocks/CU (unchanged R21).
// ---------------------------------------------------------------------------
__global__ __launch_bounds__(384, 3) void attn_kernel(
        const unsigned short* __restrict__ qkT,   // [8][4096][64] (q)
        const unsigned short* __restrict__ kfrag, // [8][128][2][64][8]
        const unsigned short* __restrict__ vfrag, // [8][8][256][64][8]
        const float* __restrict__ x,              // [8][256][4096]
        const float* __restrict__ gamma,
        float* __restrict__ out) {
    __shared__ unsigned short p_lds[2][2][4][64][8];  // 16 KiB
    __shared__ float lsum_lds[64];

    const int b   = blockIdx.x & 7;          // batch == XCD (L2 pinning)
    const int sb  = blockIdx.x >> 3;         // 0..63
    const int s0  = sb * 64;
    const int w   = threadIdx.x >> 6;        // 0..5
    const int l   = threadIdx.x & 63;
    const int l5  = l >> 5, l31 = l & 31;

    const size_t qk_base = (size_t)b * 4096 * 64;
    const size_t bx_base = (size_t)b * 256 * 4096;

    if (w < 2) {
        // ================= PRODUCER: q-rows [s0+32w, +32) ===================
        const unsigned short* qrow = qkT + qk_base + (size_t)(s0 + 32 * w + l31) * 64;
        const short8 qf0 = *(const short8*)(qrow + 8 * l5);
        const short8 qf1 = *(const short8*)(qrow + 16 + 8 * l5);
        const unsigned short* kfp = kfrag + (size_t)b * 128 * 2 * 512 + 8 * l;
        const f32x16 z16 = (f32x16)0.0f;
        float psum = 0.f;

        short8 kf00 = *(const short8*)(kfp + 0 * 512);
        short8 kf01 = *(const short8*)(kfp + 1 * 512);
        short8 kf10 = *(const short8*)(kfp + 2 * 512);
        short8 kf11 = *(const short8*)(kfp + 3 * 512);

#define EXPPACK(DD, PLO, PHI)                                                  \
    {                                                                          \
        float e0 = EXP2((DD)[0]),   e1 = EXP2((DD)[1]);                        \
        float e2 = EXP2((DD)[2]),   e3 = EXP2((DD)[3]);                        \
        float e4 = EXP2((DD)[4]),   e5 = EXP2((DD)[5]);                        \
        float e6 = EXP2((DD)[6]),   e7 = EXP2((DD)[7]);                        \
        float e8 = EXP2((DD)[8]),   e9 = EXP2((DD)[9]);                        \
        float e10 = EXP2((DD)[10]), e11 = EXP2((DD)[11]);                      \
        float e12 = EXP2((DD)[12]), e13 = EXP2((DD)[13]);                      \
        float e14 = EXP2((DD)[14]), e15 = EXP2((DD)[15]);                      \
        psum += (((e0 + e1) + (e2 + e3)) + ((e4 + e5) + (e6 + e7)))            \
              + (((e8 + e9) + (e10 + e11)) + ((e12 + e13) + (e14 + e15)));     \
        unsigned int c0, c1, c2, c3;                                           \
        asm("v_cvt_pk_bf16_f32 %0, %1, %2" : "=v"(c0) : "v"(e0), "v"(e1));     \
        asm("v_cvt_pk_bf16_f32 %0, %1, %2" : "=v"(c1) : "v"(e2), "v"(e3));     \
        asm("v_cvt_pk_bf16_f32 %0, %1, %2" : "=v"(c2) : "v"(e4), "v"(e5));     \
        asm("v_cvt_pk_bf16_f32 %0, %1, %2" : "=v"(c3) : "v"(e6), "v"(e7));     \
        u32x2 s0_ = swap32v(c0, c2);                                           \
        u32x2 s1_ = swap32v(c1, c3);                                           \
        u32x4 lo_; lo_[0] = s0_[0]; lo_[1] = s1_[0]; lo_[2] = s0_[1]; lo_[3] = s1_[1]; \
        PLO = __builtin_bit_cast(short8, lo_);                                 \
        unsigned int d0, d1, d2, d3;                                           \
        asm("v_cvt_pk_bf16_f32 %0, %1, %2" : "=v"(d0) : "v"(e8), "v"(e9));     \
        asm("v_cvt_pk_bf16_f32 %0, %1, %2" : "=v"(d1) : "v"(e10), "v"(e11));   \
        asm("v_cvt_pk_bf16_f32 %0, %1, %2" : "=v"(d2) : "v"(e12), "v"(e13));   \
        u32x2 s2_ = swap32v(d0, d2);                                           \
        asm("v_cvt_pk_bf16_f32 %0, %1, %2" : "=v"(d3) : "v"(e14), "v"(e15));   \
        u32x2 s3_ = swap32v(d1, d3);                                           \
        u32x4 hi_; hi_[0] = s2_[0]; hi_[1] = s3_[0]; hi_[2] = s2_[1]; hi_[3] = s3_[1]; \
        PHI = __builtin_bit_cast(short8, hi_);                                 \
    }

#define PRODUCE(T)                                                             \
    {                                                                          \
        const int tn_ = ((T) + 1) & 63;                                        \
        const int pb_ = (T) & 1;                                               \
        __builtin_amdgcn_s_setprio(1);                                         \
        f32x16 dd0 = __builtin_amdgcn_mfma_f32_32x32x16_bf16(kf00, qf0, z16, 0, 0, 0); \
        dd0 = __builtin_amdgcn_mfma_f32_32x32x16_bf16(kf01, qf1, dd0, 0, 0, 0);\
        f32x16 dd1 = __builtin_amdgcn_mfma_f32_32x32x16_bf16(kf10, qf0, z16, 0, 0, 0); \
        dd1 = __builtin_amdgcn_mfma_f32_32x32x16_bf16(kf11, qf1, dd1, 0, 0, 0);\
        __builtin_amdgcn_s_setprio(0);                                         \
        kf00 = *(const short8*)(kfp + (size_t)(4 * tn_ + 0) * 512);            \
        kf01 = *(const short8*)(kfp + (size_t)(4 * tn_ + 1) * 512);            \
        kf10 = *(const short8*)(kfp + (size_t)(4 * tn_ + 2) * 512);            \
        kf11 = *(const short8*)(kfp + (size_t)(4 * tn_ + 3) * 512);            \
        short8 pa0, pa1, pa2, pa3;                                             \
        EXPPACK(dd0, pa0, pa1)                                                 \
        EXPPACK(dd1, pa2, pa3)                                                 \
        *(short8*)&p_lds[pb_][w][0][l][0] = pa0;                               \
        *(short8*)&p_lds[pb_][w][1][l][0] = pa1;                               \
        *(short8*)&p_lds[pb_][w][2][l][0] = pa2;                               \
        *(short8*)&p_lds[pb_][w][3][l][0] = pa3;                               \
    }

        PRODUCE(0)
        for (int t = 1; t < 64; ++t) {
            block_sync_lds();
            PRODUCE(t)
        }
        block_sync_lds();
#undef PRODUCE
#undef EXPPACK

        psum += __shfl_xor(psum, 32);
        if (l5 == 0) lsum_lds[32 * w + l31] = psum;
        __syncthreads();
    } else {
        // ================= CONSUMER: channels [64(w-2), +64) ================
        const int cw = w - 2;                 // 0..3
        const int ct0 = 2 * cw, ct1 = 2 * cw + 1;
        const unsigned short* vfp0 = vfrag + ((size_t)(b * 8 + ct0) * 256) * 512 + 8 * l;
        const unsigned short* vfp1 = vfrag + ((size_t)(b * 8 + ct1) * 256) * 512 + 8 * l;

        f32x16 a00 = (f32x16)0.0f, a10 = (f32x16)0.0f;   // ct0: qb0, qb1
        f32x16 a01 = (f32x16)0.0f, a11 = (f32x16)0.0f;   // ct1: qb0, qb1
        short8 vA0 = *(const short8*)(vfp0 + 0 * 512);
        short8 vA1 = *(const short8*)(vfp1 + 0 * 512);
        short8 vB0 = *(const short8*)(vfp0 + 1 * 512);
        short8 vB1 = *(const short8*)(vfp1 + 1 * 512);

#define CKS(PB, KS, V0, V1)                                                    \
        {                                                                      \
            short8 p0 = *(const short8*)&p_lds[PB][0][KS][l][0];               \
            short8 p1 = *(const short8*)&p_lds[PB][1][KS][l][0];               \
            a00 = __builtin_amdgcn_mfma_f32_32x32x16_bf16(p0, V0, a00, 0, 0, 0); \
            a10 = __builtin_amdgcn_mfma_f32_32x32x16_bf16(p1, V0, a10, 0, 0, 0); \
            a01 = __builtin_amdgcn_mfma_f32_32x32x16_bf16(p0, V1, a01, 0, 0, 0); \
            a11 = __builtin_amdgcn_mfma_f32_32x32x16_bf16(p1, V1, a11, 0, 0, 0); \
        }

        for (int t = 0; t < 64; ++t) {
            block_sync_lds();
            const int pb = t & 1;
            const int tn = (t + 1) & 63;
            __builtin_amdgcn_s_setprio(1);
            CKS(pb, 0, vA0, vA1)
            __builtin_amdgcn_s_setprio(0);
            vA0 = *(const short8*)(vfp0 + (size_t)(4 * t + 2) * 512);
            vA1 = *(const short8*)(vfp1 + (size_t)(4 * t + 2) * 512);
            __builtin_amdgcn_s_setprio(1);
            CKS(pb, 1, vB0, vB1)
            __builtin_amdgcn_s_setprio(0);
            vB0 = *(const short8*)(vfp0 + (size_t)(4 * t + 3) * 512);
            vB1 = *(const short8*)(vfp1 + (size_t)(4 * t + 3) * 512);
            __builtin_amdgcn_s_setprio(1);
            CKS(pb, 2, vA0, vA1)
            __builtin_amdgcn_s_setprio(0);
            vA0 = *(const short8*)(vfp0 + (size_t)(4 * tn + 0) * 512);
            vA1 = *(const short8*)(vfp1 + (size_t)(4 * tn + 0) * 512);
            __builtin_amdgcn_s_setprio(1);
            CKS(pb, 3, vB0, vB1)
            __builtin_amdgcn_s_setprio(0);
            vB0 = *(const short8*)(vfp0 + (size_t)(4 * tn + 1) * 512);
            vB1 = *(const short8*)(vfp1 + (size_t)(4 * tn + 1) * 512);
        }
#undef CKS
        __syncthreads();     // producers' lsum_lds writes now visible

        const float g = gamma[0];
#pragma unroll
        for (int rq = 0; rq < 4; ++rq) {
            const int rbase = 8 * rq + 4 * l5;
#define STORE_QB(ACC, QB, CT)                                                  \
            {                                                                  \
                f32x4 ls = *(const f32x4*)&lsum_lds[32 * (QB) + rbase];        \
                f32x4 gi;                                                      \
                gi[0] = g / ls[0]; gi[1] = g / ls[1];                          \
                gi[2] = g / ls[2]; gi[3] = g / ls[3];                          \
                size_t off = bx_base + (size_t)(32 * (CT) + l31) * 4096 + s0 + 32 * (QB) + rbase; \
                f32x4 xv = *(const f32x4*)(x + off);                           \
                f32x4 o;                                                       \
                o[0] = gi[0] * (ACC)[4 * rq + 0] + xv[0];                      \
                o[1] = gi[1] * (ACC)[4 * rq + 1] + xv[1];                      \
                o[2] = gi[2] * (ACC)[4 * rq + 2] + xv[2];                      \
                o[3] = gi[3] * (ACC)[4 * rq + 3] + xv[3];                      \
                *(f32x4*)(out + off) = o;                                      \
            }
            STORE_QB(a00, 0, ct0)
            STORE_QB(a10, 1, ct0)
            STORE_QB(a01, 0, ct1)
            STORE_QB(a11, 1, ct1)
#undef STORE_QB
        }
    }
}

// ---------------------------------------------------------------------------
extern "C" void kernel_launch(void* const* d_in, const int* in_sizes, int n_in,
                              void* d_out, int out_size, void* d_ws, size_t ws_size,
                              hipStream_t stream) {
    const float* x     = (const float*)d_in[0];
    const float* wqk   = (const float*)d_in[1];
    const float* wv    = (const float*)d_in[2];
    const float* gamma = (const float*)d_in[3];
    float* out = (float*)d_out;

    char* ws = (char*)d_ws;
    unsigned short* W     = (unsigned short*)(ws);                      // 160 KiB
    unsigned short* qkT   = (unsigned short*)(ws + 163840);             // 4 MiB
    unsigned short* xT    = (unsigned short*)(ws + 4358144);            // 16 MiB
    unsigned short* vfrag = (unsigned short*)(ws + 21135360);           // 16 MiB
    unsigned short* kfrag = (unsigned short*)(ws + 37912576);           // 2 MiB

    hipLaunchKernelGGL(transpose_prep_kernel, dim3(2368), dim3(256), 0, stream,
                       x, xT, wqk, wv, W);
    hipLaunchKernelGGL(proj_kernel, dim3(512), dim3(256), 0, stream,
                       W, xT, qkT, kfrag, vfrag);
    hipLaunchKernelGGL(attn_kernel, dim3(512), dim3(384), 0, stream,
                       qkT, kfrag, vfrag, x, gamma, out);
}